// Round 16
// baseline (257.360 us; speedup 1.0000x reference)
//
#include <hip/hip_runtime.h>
#include <hip/hip_bf16.h>
#include <math.h>

#define DD 128
#define QW 896       // 256(Q)+256(K)+256(V)+128(skip)
#define NB 125       // coarse buckets (dst>>7), 128 nodes each
#define BCAP 4096

typedef _Float16 f16x8 __attribute__((ext_vector_type(8)));
typedef _Float16 f16x4 __attribute__((ext_vector_type(4)));
typedef _Float16 f16x2 __attribute__((ext_vector_type(2)));
typedef float f32x4 __attribute__((ext_vector_type(4)));
typedef float f32x2 __attribute__((ext_vector_type(2)));

__device__ __forceinline__ float fdot2f(f16x2 a, f16x2 b, float c) {
#if __has_builtin(__builtin_amdgcn_fdot2)
  return __builtin_amdgcn_fdot2(a, b, c, false);
#else
  return fmaf((float)a[0], (float)b[0], fmaf((float)a[1], (float)b[1], c));
#endif
}

// ---- fp8 e4m3 (OCP) helpers: encoder flushes subnormals (|v|<2^-6 -> 0) ----
__device__ __forceinline__ unsigned e4m3b(float v) {
  float a = fabsf(v);
  unsigned s = (__float_as_uint(v) >> 24) & 0x80u;
  if (!(a >= 0.015625f)) return s;
  if (a > 448.f) a = 448.f;
  unsigned u = __float_as_uint(a) + (1u << 19);  // round-half-up into m3
  int e = (int)((u >> 23) & 255) - 120;
  if (e > 15) return s | 0x7Eu;                  // clamp to 448
  return s | ((unsigned)e << 3) | ((u >> 20) & 7u);
}
__device__ __forceinline__ float e4m3f(unsigned b) {
  unsigned em = b & 0x7Fu;
  unsigned s = (b & 0x80u) << 24;
  if (em == 0) return __uint_as_float(s);
  return __uint_as_float(s | (((em >> 3) + 120u) << 23) | ((em & 7u) << 20));
}
template <bool HI>
__device__ __forceinline__ f32x2 fp8x2f(unsigned w) {
#if __has_builtin(__builtin_amdgcn_cvt_pk_f32_fp8)
  return __builtin_amdgcn_cvt_pk_f32_fp8((int)w, HI);
#else
  unsigned h = HI ? (w >> 16) : w;
  f32x2 r; r[0] = e4m3f(h & 255u); r[1] = e4m3f((h >> 8) & 255u);
  return r;
#endif
}

// ---------------- CSR build: two-level LDS counting sort (no memsets) ----------------
__global__ __launch_bounds__(256) void csr_count(const int* __restrict__ edst,
                                                 int* __restrict__ bparts, int E) {
  __shared__ int h[NB];
  const int tid = threadIdx.x;
  if (tid < NB) h[tid] = 0;
  __syncthreads();
  const int e0 = blockIdx.x * 2048;
  for (int k = 0; k < 8; ++k) {
    int e = e0 + k * 256 + tid;
    if (e < E) atomicAdd(&h[edst[e] >> 7], 1);
  }
  __syncthreads();
  if (tid < 128) bparts[blockIdx.x * 128 + tid] = (tid < NB) ? h[tid] : 0;
}

__global__ __launch_bounds__(128) void csr_scan(const int* __restrict__ bparts, int nblk,
                                                int* __restrict__ bbase,
                                                int* __restrict__ bcursor,
                                                int* __restrict__ offs, int E, int Nn) {
  __shared__ int sc[128];
  const int tid = threadIdx.x;
  int s = 0;
  for (int b = 0; b < nblk; ++b) s += bparts[b * 128 + tid];
  sc[tid] = (tid < NB) ? s : 0;
  __syncthreads();
  for (int d = 1; d < 128; d <<= 1) {
    int t = (tid >= d) ? sc[tid - d] : 0;
    __syncthreads();
    sc[tid] += t;
    __syncthreads();
  }
  const int excl = tid ? sc[tid - 1] : 0;
  if (tid < NB) { bbase[tid] = excl; bcursor[tid] = excl; }
  if (tid == 0) { bbase[NB] = E; offs[Nn] = E; }
}

__global__ __launch_bounds__(256) void csr_scatter(const int* __restrict__ edst,
                                                   const int* __restrict__ esrc,
                                                   const int* __restrict__ etyp,
                                                   int* __restrict__ bcursor,
                                                   unsigned* __restrict__ ebuf, int E) {
  __shared__ int h[NB], cur[NB];
  const int tid = threadIdx.x;
  if (tid < NB) h[tid] = 0;
  __syncthreads();
  const int e0 = blockIdx.x * 2048;
  int dd[8];
  for (int k = 0; k < 8; ++k) {
    int e = e0 + k * 256 + tid;
    dd[k] = (e < E) ? edst[e] : -1;
    if (dd[k] >= 0) atomicAdd(&h[dd[k] >> 7], 1);
  }
  __syncthreads();
  if (tid < NB && h[tid]) cur[tid] = atomicAdd(&bcursor[tid], h[tid]);
  __syncthreads();
  for (int k = 0; k < 8; ++k) {
    int e = e0 + k * 256 + tid;
    if (dd[k] >= 0) {
      int pos = atomicAdd(&cur[dd[k] >> 7], 1);
      ebuf[pos] = (unsigned)esrc[e] | ((unsigned)etyp[e] << 14) |
                  ((unsigned)(dd[k] & 127) << 18);
    }
  }
}

__global__ __launch_bounds__(256) void csr_fine(const unsigned* __restrict__ ebuf,
                                                const int* __restrict__ bbase,
                                                unsigned* __restrict__ epk,
                                                int* __restrict__ offs,
                                                int* __restrict__ dparts) {
  __shared__ unsigned sed[BCAP];
  __shared__ unsigned sout[BCAP];
  __shared__ int fh[128], sc[128], fc[128], hb[64];
  const int b = blockIdx.x, tid = threadIdx.x;
  const int base = bbase[b], cnt = bbase[b + 1] - base;
  for (int idx = tid; idx < cnt; idx += 256) sed[idx] = ebuf[base + idx];
  if (tid < 128) fh[tid] = 0;
  if (tid < 64) hb[tid] = 0;
  __syncthreads();
  for (int idx = tid; idx < cnt; idx += 256) atomicAdd(&fh[(sed[idx] >> 18) & 127], 1);
  __syncthreads();
  if (tid < 128) sc[tid] = fh[tid];
  __syncthreads();
  for (int d = 1; d < 128; d <<= 1) {
    int t = (tid < 128 && tid >= d) ? sc[tid - d] : 0;
    __syncthreads();
    if (tid < 128) sc[tid] += t;
    __syncthreads();
  }
  if (tid < 128) {
    const int excl = tid ? sc[tid - 1] : 0;
    offs[b * 128 + tid] = base + excl;
    fc[tid] = excl;
    atomicAdd(&hb[min(fh[tid], 63)], 1);
  }
  __syncthreads();
  if (tid < 64) dparts[b * 64 + tid] = hb[tid];
  for (int idx = tid; idx < cnt; idx += 256) {
    const unsigned v = sed[idx];
    const int pos = atomicAdd(&fc[(v >> 18) & 127], 1);
    sout[pos] = (v & 0x3FFF) | (((v >> 14) & 0xF) << 18);  // src | typ<<18
  }
  __syncthreads();
  for (int idx = tid; idx < cnt; idx += 256) epk[base + idx] = sout[idx];
}

__global__ __launch_bounds__(64) void deg_scan(const int* __restrict__ dparts, int nblk,
                                               int* __restrict__ dcur) {
  __shared__ int tot[64];
  const int t = threadIdx.x;
  int s = 0;
  for (int b = 0; b < nblk; ++b) s += dparts[b * 64 + t];
  tot[t] = s;
  __syncthreads();
  int acc = 0;
  for (int d = t + 1; d < 64; ++d) acc += tot[d];
  dcur[t] = acc;
}

__global__ __launch_bounds__(256) void deg_order(const int* __restrict__ offs,
                                                 int* __restrict__ dcur,
                                                 int* __restrict__ order, int Nn) {
  __shared__ int h[64], cbase[64];
  const int tid = threadIdx.x;
  const int i = blockIdx.x * 256 + tid;
  if (tid < 64) h[tid] = 0;
  __syncthreads();
  int bk = -1;
  if (i < Nn) {
    bk = min(offs[i + 1] - offs[i], 63);
    atomicAdd(&h[bk], 1);
  }
  __syncthreads();
  if (tid < 64) {
    const int c = h[tid];
    cbase[tid] = c ? atomicAdd(&dcur[tid], c) : 0;
    h[tid] = 0;
  }
  __syncthreads();
  if (bk >= 0) {
    const int pos = cbase[bk] + atomicAdd(&h[bk], 1);
    order[pos] = i;
  }
}

// ---------------- pp_cast: all parallel precompute + fw2 transpose tail blocks ------
__global__ __launch_bounds__(256) void pp_cast(
    const float* __restrict__ Wq, const float* __restrict__ Wk,
    const float* __restrict__ Wv, const float* __restrict__ Wsk,
    const float* __restrict__ bq, const float* __restrict__ bk,
    const float* __restrict__ bv, const float* __restrict__ bsk,
    const float* __restrict__ hemb, const float* __restrict__ We,
    const float* __restrict__ x,
    const float* __restrict__ fw1, const float* __restrict__ fb1,
    const float* __restrict__ fw2, const float* __restrict__ fb2,
    _Float16* __restrict__ WcatT, float* __restrict__ Wcat, float* __restrict__ bcat,
    _Float16* __restrict__ epth, _Float16* __restrict__ xh,
    _Float16* __restrict__ fw1h, _Float16* __restrict__ fw2Th,
    float* __restrict__ bfv, float* __restrict__ bzero, int Nn, int nb0) {
  __shared__ _Float16 tile[64][65];
  if (blockIdx.x >= nb0) {  // fw2 transpose+cast tail blocks (32 tiles)
    const int tb = blockIdx.x - nb0;
    const int l = tb >> 4, r2 = tb & 15;
    const int k0 = (r2 >> 1) << 6, j0 = (r2 & 1) << 6;
    const size_t base = (size_t)l * 65536;
    const int tid = threadIdx.x;
    for (int idx = tid; idx < 4096; idx += 256) {
      int rr = idx >> 6, cc = idx & 63;
      tile[rr][cc] = (_Float16)fw2[base + (size_t)(k0 + rr) * 128 + j0 + cc];
    }
    __syncthreads();
    for (int idx = tid; idx < 4096; idx += 256) {
      int rr = idx >> 6, cc = idx & 63;
      fw2Th[base + (size_t)(j0 + rr) * 512 + k0 + cc] = tile[cc][rr];
    }
    return;
  }
  int t = blockIdx.x * 256 + threadIdx.x;
  if (t < 256) {  // bfv[l][j]
    int l = t >> 7, j = t & 127;
    const float* b1 = fb1 + l * 512;
    const float* w2 = fw2 + (size_t)l * 65536 + j;
    float s0 = fb2[l * 128 + j], s1 = 0.f, s2 = 0.f, s3 = 0.f;
    for (int k = 0; k < 512; k += 4) {
      s0 = fmaf(b1[k], w2[(size_t)k * 128], s0);
      s1 = fmaf(b1[k + 1], w2[(size_t)(k + 1) * 128], s1);
      s2 = fmaf(b1[k + 2], w2[(size_t)(k + 2) * 128], s2);
      s3 = fmaf(b1[k + 3], w2[(size_t)(k + 3) * 128], s3);
    }
    bfv[t] = ((s0 + s1) + (s2 + s3));
    return;
  }
  t -= 256;
  if (t < 2560) {  // eproj
    int ty = t >> 8, col = t & 255;
    float s0 = 0.f, s1 = 0.f, s2 = 0.f, s3 = 0.f;
    const float* hr = hemb + ty * 128;
    for (int c = 0; c < 128; c += 4) {
      s0 = fmaf(hr[c], We[c * 256 + col], s0);
      s1 = fmaf(hr[c + 1], We[(c + 1) * 256 + col], s1);
      s2 = fmaf(hr[c + 2], We[(c + 2) * 256 + col], s2);
      s3 = fmaf(hr[c + 3], We[(c + 3) * 256 + col], s3);
    }
    epth[t] = (_Float16)((s0 + s1) + (s2 + s3));
    return;
  }
  t -= 2560;
  if (t < 114688) {  // WcatT f16 [896][128] + Wcat f32 [128][896]
    int n = t >> 7, k = t & 127;
    float v;
    if (n < 256) v = Wq[k * 256 + n];
    else if (n < 512) v = Wk[k * 256 + (n - 256)];
    else if (n < 768) v = Wv[k * 256 + (n - 512)];
    else v = Wsk[k * 128 + (n - 768)];
    WcatT[t] = (_Float16)v;
    Wcat[k * 896 + n] = v;
    return;
  }
  t -= 114688;
  if (t < 896) {
    float v;
    if (t < 256) v = bq[t];
    else if (t < 512) v = bk[t - 256];
    else if (t < 768) v = bv[t - 512];
    else v = bsk[t - 768];
    bcat[t] = v;
    return;
  }
  t -= 896;
  if (t < 1024) { bzero[t] = 0.f; return; }
  t -= 1024;
  if (t < 16384) {  // fw1 cast
    float4 v0 = *reinterpret_cast<const float4*>(fw1 + (size_t)t * 8);
    float4 v1 = *reinterpret_cast<const float4*>(fw1 + (size_t)t * 8 + 4);
    f16x8 o;
    o[0] = (_Float16)v0.x; o[1] = (_Float16)v0.y; o[2] = (_Float16)v0.z; o[3] = (_Float16)v0.w;
    o[4] = (_Float16)v1.x; o[5] = (_Float16)v1.y; o[6] = (_Float16)v1.z; o[7] = (_Float16)v1.w;
    *reinterpret_cast<f16x8*>(fw1h + (size_t)t * 8) = o;
    return;
  }
  t -= 16384;
  if (t < Nn * 16) {  // cast x -> f16
    float4 v0 = *reinterpret_cast<const float4*>(x + (size_t)t * 8);
    float4 v1 = *reinterpret_cast<const float4*>(x + (size_t)t * 8 + 4);
    f16x8 o;
    o[0] = (_Float16)v0.x; o[1] = (_Float16)v0.y; o[2] = (_Float16)v0.z; o[3] = (_Float16)v0.w;
    o[4] = (_Float16)v1.x; o[5] = (_Float16)v1.y; o[6] = (_Float16)v1.z; o[7] = (_Float16)v1.w;
    *reinterpret_cast<f16x8*>(xh + (size_t)t * 8) = o;
  }
}

// ---------------- pp_bmid: bmid = [bfv0 | bfv0@Wcat + bcat] ----------------
__global__ __launch_bounds__(256) void pp_bmid(const float* __restrict__ bfv,
                                               const float* __restrict__ Wcat,
                                               const float* __restrict__ bcat,
                                               float* __restrict__ bmid) {
  int t = blockIdx.x * 256 + threadIdx.x;
  if (t >= 1024) return;
  if (t < 128) { bmid[t] = bfv[t]; return; }
  int n = t - 128;
  float s0 = bcat[n], s1 = 0.f, s2 = 0.f, s3 = 0.f;
  for (int c = 0; c < 128; c += 4) {
    s0 = fmaf(bfv[c], Wcat[c * 896 + n], s0);
    s1 = fmaf(bfv[c + 1], Wcat[(c + 1) * 896 + n], s1);
    s2 = fmaf(bfv[c + 2], Wcat[(c + 2) * 896 + n], s2);
    s3 = fmaf(bfv[c + 3], Wcat[(c + 3) * 896 + n], s3);
  }
  bmid[t] = ((s0 + s1) + (s2 + s3));
}

// ---------------- Wf[z] = fw1h[z] @ fw2Th[z]^T  (grid.z=2) -------------
__global__ __launch_bounds__(256) void wf_gemm(const _Float16* __restrict__ fw1h,
                                               const _Float16* __restrict__ fw2Th,
                                               float* __restrict__ Wf,
                                               _Float16* __restrict__ Wfh,
                                               _Float16* __restrict__ BtMid0) {
  const int z = blockIdx.z;
  const _Float16* A = fw1h + z * 65536;
  const _Float16* Bt = fw2Th + z * 65536;
  const int tid = threadIdx.x;
  const int wid = tid >> 6, lane = tid & 63;
  const int wr = wid >> 1, wc = wid & 1;
  const int il = lane & 15, g = lane >> 4;
  const int row0 = wr * 64, col0 = wc * 64;
  const _Float16* Ap = A + (size_t)(row0 + il) * 512 + 8 * g;
  const _Float16* Bp = Bt + (size_t)(col0 + il) * 512 + 8 * g;
  f32x4 acc[4][4];
#pragma unroll
  for (int a = 0; a < 4; ++a)
#pragma unroll
    for (int b = 0; b < 4; ++b) acc[a][b] = (f32x4){0.f, 0.f, 0.f, 0.f};
  for (int k0 = 0; k0 < 512; k0 += 32) {
    f16x8 af[4], bf[4];
#pragma unroll
    for (int f = 0; f < 4; ++f) {
      af[f] = *reinterpret_cast<const f16x8*>(Ap + (size_t)(f * 16) * 512 + k0);
      bf[f] = *reinterpret_cast<const f16x8*>(Bp + (size_t)(f * 16) * 512 + k0);
    }
#pragma unroll
    for (int fi = 0; fi < 4; ++fi)
#pragma unroll
      for (int fj = 0; fj < 4; ++fj)
        acc[fi][fj] = __builtin_amdgcn_mfma_f32_16x16x32_f16(af[fi], bf[fj], acc[fi][fj], 0, 0, 0);
  }
#pragma unroll
  for (int fj = 0; fj < 4; ++fj) {
    const int col = col0 + fj * 16 + il;
#pragma unroll
    for (int fi = 0; fi < 4; ++fi) {
#pragma unroll
      for (int i = 0; i < 4; ++i) {
        const int row = row0 + fi * 16 + g * 4 + i;
        const float v = acc[fi][fj][i];
        Wf[z * 16384 + row * 128 + col] = v;
        if (z == 0) {
          Wfh[row * 128 + col] = (_Float16)v;
          BtMid0[col * 128 + row] = (_Float16)v;
        }
      }
    }
  }
}

// ---------------- MFMA f16 GEMM (K==128): A-tile in LDS (32KB, XOR swizzle),
// B fragments direct from global (B is small & L2-resident).
template <bool HAS_CFH, bool HAS_CH, bool HAS_CHT>
__global__ __launch_bounds__(256) void gemm_tn_f16(const _Float16* __restrict__ A,
                                                   const _Float16* __restrict__ Bt,
                                                   const float* __restrict__ bias,
                                                   _Float16* __restrict__ Cfh, int NF,
                                                   _Float16* __restrict__ Ch, int choff, int ldh,
                                                   _Float16* __restrict__ ChT, int ldt,
                                                   int M, int N, int K) {
  __shared__ __align__(16) char smA[32768];
  const int tid = threadIdx.x;
  const int wid = tid >> 6, lane = tid & 63;
  const int wr = wid >> 1, wc = wid & 1;
  const int il = lane & 15, g = lane >> 4;
  const int row0 = blockIdx.y * 128;
  const int col0 = blockIdx.x * 128;
  {
    const f16x8* Ag = reinterpret_cast<const f16x8*>(A + (size_t)row0 * 128);
#pragma unroll
    for (int it = 0; it < 8; ++it) {
      const int c = it * 256 + tid;
      const int r = c >> 4;
      const int off = r * 256 + (((c & 15) << 4) ^ ((r & 7) << 4));
      *reinterpret_cast<f16x8*>(smA + off) = Ag[c];
    }
  }
  __syncthreads();
  const _Float16* Bp = Bt + (size_t)(col0 + wc * 64 + il) * 128 + 8 * g;
  f32x4 acc[4][4];
#pragma unroll
  for (int a = 0; a < 4; ++a)
#pragma unroll
    for (int b = 0; b < 4; ++b) acc[a][b] = (f32x4){0.f, 0.f, 0.f, 0.f};
#pragma unroll
  for (int ks = 0; ks < 4; ++ks) {
    const int kb = ks * 64 + g * 16;       // byte offset of lane's 16B K-slice (LDS)
    const int ke = ks * 32;                // element offset for global B
    f16x8 af[4], bf[4];
#pragma unroll
    for (int f = 0; f < 4; ++f) {
      const int ra = wr * 64 + f * 16 + il;
      af[f] = *reinterpret_cast<const f16x8*>(smA + ra * 256 + (kb ^ ((ra & 7) << 4)));
      bf[f] = *reinterpret_cast<const f16x8*>(Bp + (size_t)(f * 16) * 128 + ke);
    }
#pragma unroll
    for (int fi = 0; fi < 4; ++fi)
#pragma unroll
      for (int fj = 0; fj < 4; ++fj)
        acc[fi][fj] = __builtin_amdgcn_mfma_f32_16x16x32_f16(bf[fj], af[fi], acc[fi][fj], 0, 0, 0);
  }
#pragma unroll
  for (int fi = 0; fi < 4; ++fi) {
    const int row = row0 + wr * 64 + fi * 16 + il;
#pragma unroll
    for (int fj = 0; fj < 4; ++fj) {
      const int col = col0 + wc * 64 + fj * 16 + g * 4;
      const float4 b4 = *reinterpret_cast<const float4*>(bias + col);
      f16x4 o;
      o[0] = (_Float16)(acc[fi][fj][0] + b4.x);
      o[1] = (_Float16)(acc[fi][fj][1] + b4.y);
      o[2] = (_Float16)(acc[fi][fj][2] + b4.z);
      o[3] = (_Float16)(acc[fi][fj][3] + b4.w);
      if constexpr (HAS_CFH) {
        if (col < NF) *reinterpret_cast<f16x4*>(&Cfh[(size_t)row * NF + col]) = o;
      }
      if constexpr (HAS_CH) {
        if (col >= choff) *reinterpret_cast<f16x4*>(&Ch[(size_t)row * ldh + (col - choff)]) = o;
      }
      if constexpr (HAS_CHT) {
#pragma unroll
        for (int i = 0; i < 4; ++i) ChT[(size_t)(col + i) * ldt + row] = o[i];
      }
    }
  }
}

// ---------------- kv_quant: K/V f16 -> fp8 e4m3, coalesced 16B stores ----------------
// kvq[node][grp<32][16B] = [K ch 8g..8g+7 | V ch 8g..8g+7]
__global__ __launch_bounds__(256) void kv_quant(const _Float16* __restrict__ QKVSh,
                                                unsigned char* __restrict__ kvq, int total) {
  int t = blockIdx.x * 256 + threadIdx.x;
  if (t >= total) return;
  const int node = t >> 5, grp = t & 31;
  const _Float16* kp = QKVSh + (size_t)node * QW + 256 + grp * 8;
  f16x8 kv = *reinterpret_cast<const f16x8*>(kp);
  f16x8 vv = *reinterpret_cast<const f16x8*>(kp + 256);
  uint4 o;
  o.x = e4m3b((float)kv[0]) | (e4m3b((float)kv[1]) << 8) |
        (e4m3b((float)kv[2]) << 16) | (e4m3b((float)kv[3]) << 24);
  o.y = e4m3b((float)kv[4]) | (e4m3b((float)kv[5]) << 8) |
        (e4m3b((float)kv[6]) << 16) | (e4m3b((float)kv[7]) << 24);
  o.z = e4m3b((float)vv[0]) | (e4m3b((float)vv[1]) << 8) |
        (e4m3b((float)vv[2]) << 16) | (e4m3b((float)vv[3]) << 24);
  o.w = e4m3b((float)vv[4]) | (e4m3b((float)vv[5]) << 8) |
        (e4m3b((float)vv[6]) << 16) | (e4m3b((float)vv[7]) << 24);
  *reinterpret_cast<uint4*>(kvq + (size_t)node * 512 + grp * 16) = o;
}

// ---------------- fused per-node attention: fp8 K/V gather, single-pass online softmax --
__global__ __launch_bounds__(256) void node_attn_ln_kernel(
    const _Float16* __restrict__ QKVSh, const unsigned char* __restrict__ kvq,
    const _Float16* __restrict__ epth,
    const _Float16* __restrict__ hpre,
    const int* __restrict__ offs, const unsigned* __restrict__ epk,
    const int* __restrict__ order,
    const float* __restrict__ gamma, const float* __restrict__ beta,
    _Float16* __restrict__ hlnh, int Nn) {
  __shared__ float sqe[4][2][10];
  __shared__ __align__(16) _Float16 elds[2560];
  const int tid = threadIdx.x;
  for (int t = tid; t < 1280; t += 256)
    reinterpret_cast<unsigned*>(elds)[t] = reinterpret_cast<const unsigned*>(epth)[t];
  __syncthreads();
  const int w = tid >> 6, lane = tid & 63;
  const int i = order[blockIdx.x * 4 + w];
  const int sub = lane >> 5;
  const int r = lane & 31;
  const int half = r >> 4;
  const int co = r << 3;
  const float scale = 0.08838834764831845f;  // 1/sqrt(128)
  f16x8 qh = *reinterpret_cast<const f16x8*>(QKVSh + (size_t)i * QW + co);
  const f16x2* q2 = reinterpret_cast<const f16x2*>(&qh);
  float qf[8];
#pragma unroll
  for (int t = 0; t < 8; ++t) qf[t] = (float)qh[t] * scale;
#pragma unroll
  for (int ty = 0; ty < 10; ++ty) {
    f16x8 ev = *reinterpret_cast<const f16x8*>(elds + (ty << 8) + co);
    const f16x2* e2 = reinterpret_cast<const f16x2*>(&ev);
    float s = 0.f;
#pragma unroll
    for (int p2 = 0; p2 < 4; ++p2) s = fdot2f(q2[p2], e2[p2], s);
    s += __shfl_xor(s, 1); s += __shfl_xor(s, 2);
    s += __shfl_xor(s, 4); s += __shfl_xor(s, 8);
    if (lane < 32 && (r & 15) == 0) sqe[w][half][ty] = s * scale;
  }
  __threadfence_block();
  float m_me = -1e30f, s_me = 0.f;
  float acc[8] = {0.f};
  const int ebeg = offs[i], eend = offs[i + 1];
  if (ebeg < eend) {
    const int last = eend - 1;
    unsigned pk0 = epk[min(ebeg + sub, last)];
    unsigned pk1 = epk[min(ebeg + 2 + sub, last)];
    uint4 kv0 = *reinterpret_cast<const uint4*>(kvq + (size_t)(pk0 & 0x3FFFF) * 512 + (r << 4));
    uint4 kv1 = *reinterpret_cast<const uint4*>(kvq + (size_t)(pk1 & 0x3FFFF) * 512 + (r << 4));
    for (int j = ebeg; j < eend; j += 2) {
      const uint4 cur = kv0;
      const unsigned pkc = pk0;
      kv0 = kv1; pk0 = pk1;
      pk1 = epk[min(j + 4 + sub, last)];
      kv1 = *reinterpret_cast<const uint4*>(kvq + (size_t)(pk1 & 0x3FFFF) * 512 + (r << 4));
      const int tyc = pkc >> 18;
      // decode K (8 fp8 in cur.x, cur.y), dot with pre-scaled qf
      f32x2 k0 = fp8x2f<false>(cur.x), k1 = fp8x2f<true>(cur.x);
      f32x2 k2 = fp8x2f<false>(cur.y), k3 = fp8x2f<true>(cur.y);
      float d = qf[0] * k0[0];
      d = fmaf(qf[1], k0[1], d); d = fmaf(qf[2], k1[0], d); d = fmaf(qf[3], k1[1], d);
      d = fmaf(qf[4], k2[0], d); d = fmaf(qf[5], k2[1], d);
      d = fmaf(qf[6], k3[0], d); d = fmaf(qf[7], k3[1], d);
      d += __shfl_xor(d, 1); d += __shfl_xor(d, 2);
      d += __shfl_xor(d, 4); d += __shfl_xor(d, 8);
      d += sqe[w][half][tyc];
      float e;
      if (d > m_me + 8.f) {  // defer-max: fires ~once per node
        const float rr = __expf(m_me - d);
        s_me *= rr;
#pragma unroll
        for (int t = 0; t < 8; ++t) acc[t] *= rr;
        m_me = d;
        e = 1.f;
      } else {
        e = __expf(d - m_me);
      }
      if (j + sub >= eend) e = 0.f;  // odd-tail mask
      s_me += e;
      // decode V (cur.z, cur.w); acc += (v + ept)*e
      f32x2 v0 = fp8x2f<false>(cur.z), v1 = fp8x2f<true>(cur.z);
      f32x2 v2 = fp8x2f<false>(cur.w), v3 = fp8x2f<true>(cur.w);
      f16x8 ec = *reinterpret_cast<const f16x8*>(elds + (tyc << 8) + co);
      acc[0] = fmaf(v0[0], e, acc[0]); acc[1] = fmaf(v0[1], e, acc[1]);
      acc[2] = fmaf(v1[0], e, acc[2]); acc[3] = fmaf(v1[1], e, acc[3]);
      acc[4] = fmaf(v2[0], e, acc[4]); acc[5] = fmaf(v2[1], e, acc[5]);
      acc[6] = fmaf(v3[0], e, acc[6]); acc[7] = fmaf(v3[1], e, acc[7]);
#pragma unroll
      for (int t = 0; t < 8; ++t) acc[t] = fmaf((float)ec[t], e, acc[t]);
    }
  }
  // merge the two edge slots (lane^32 holds same (half, co))
  const float mo = __shfl_xor(m_me, 32);
  const float so = __shfl_xor(s_me, 32);
  const float mf = fmaxf(m_me, mo);
  const float sc_me = __expf(m_me - mf);
  const float sc_o = __expf(mo - mf);
  const float s_tot = s_me * sc_me + so * sc_o;
  const float invme = 1.f / (s_tot + 1e-16f);
  float g[8];
#pragma unroll
  for (int t = 0; t < 8; ++t) {
    const float ao = __shfl_xor(acc[t], 32);
    const float a = (acc[t] * sc_me + ao * sc_o) * invme;
    g[t] = 0.5f * (a + __shfl_xor(a, 16));  // head mean
  }
  const int cm = (r & 15) << 3;
  f16x8 sk = *reinterpret_cast<const f16x8*>(QKVSh + (size_t)i * QW + 768 + cm);
  f16x8 pr = *reinterpret_cast<const f16x8*>(hpre + (size_t)i * DD + cm);
  float xv[8];
#pragma unroll
  for (int t = 0; t < 8; ++t) xv[t] = g[t] + (float)sk[t] + (float)pr[t];
  float sm = 0.f;
#pragma unroll
  for (int t = 0; t < 8; ++t) sm += xv[t];
  sm += __shfl_xor(sm, 1); sm += __shfl_xor(sm, 2);
  sm += __shfl_xor(sm, 4); sm += __shfl_xor(sm, 8);
  const float mu = sm * (1.f / 128.f);
  float dx[8], vvs = 0.f;
#pragma unroll
  for (int t = 0; t < 8; ++t) { dx[t] = xv[t] - mu; vvs += dx[t] * dx[t]; }
  vvs += __shfl_xor(vvs, 1); vvs += __shfl_xor(vvs, 2);
  vvs += __shfl_xor(vvs, 4); vvs += __shfl_xor(vvs, 8);
  const float rstd = rsqrtf(vvs * (1.f / 128.f) + 1e-6f);
  if (lane < 16) {
    float4 gm0 = *reinterpret_cast<const float4*>(gamma + cm);
    float4 gm1 = *reinterpret_cast<const float4*>(gamma + cm + 4);
    float4 bt0 = *reinterpret_cast<const float4*>(beta + cm);
    float4 bt1 = *reinterpret_cast<const float4*>(beta + cm + 4);
    f16x8 o;
    o[0] = (_Float16)(dx[0] * rstd * gm0.x + bt0.x);
    o[1] = (_Float16)(dx[1] * rstd * gm0.y + bt0.y);
    o[2] = (_Float16)(dx[2] * rstd * gm0.z + bt0.z);
    o[3] = (_Float16)(dx[3] * rstd * gm0.w + bt0.w);
    o[4] = (_Float16)(dx[4] * rstd * gm1.x + bt1.x);
    o[5] = (_Float16)(dx[5] * rstd * gm1.y + bt1.y);
    o[6] = (_Float16)(dx[6] * rstd * gm1.z + bt1.z);
    o[7] = (_Float16)(dx[7] * rstd * gm1.w + bt1.w);
    *reinterpret_cast<f16x8*>(hlnh + (size_t)i * DD + cm) = o;
  }
}

// ---------------- final: gather mask rows of hln1, apply layer-1 fused FFN ----------------
__global__ __launch_bounds__(128) void final_kernel(const _Float16* __restrict__ hlnh1,
                                                    const float* __restrict__ Wf,
                                                    const float* __restrict__ bfv,
                                                    const int* __restrict__ midx,
                                                    float* __restrict__ out) {
  __shared__ float rowv[128];
  const int b = blockIdx.x, j = threadIdx.x;
  const int row = midx[b];
  rowv[j] = (float)hlnh1[(size_t)row * DD + j];
  __syncthreads();
  const float* w1 = Wf + 16384 + j;
  float s = bfv[128 + j];
#pragma unroll 4
  for (int c = 0; c < 128; ++c) s = fmaf(rowv[c], w1[c * 128], s);
  out[b * DD + j] = s;
}

extern "C" void kernel_launch(void* const* d_in, const int* in_sizes, int n_in,
                              void* d_out, int out_size, void* d_ws, size_t ws_size,
                              hipStream_t stream) {
  const float* x    = (const float*)d_in[0];
  const float* hemb = (const float*)d_in[1];
  const float* Wq   = (const float*)d_in[2];
  const float* bq   = (const float*)d_in[3];
  const float* Wk   = (const float*)d_in[4];
  const float* bk   = (const float*)d_in[5];
  const float* Wv   = (const float*)d_in[6];
  const float* bv   = (const float*)d_in[7];
  const float* We   = (const float*)d_in[8];
  const float* Wsk  = (const float*)d_in[9];
  const float* bsk  = (const float*)d_in[10];
  const float* lng  = (const float*)d_in[11];
  const float* lnb  = (const float*)d_in[12];
  const float* fw1  = (const float*)d_in[13];
  const float* fb1  = (const float*)d_in[14];
  const float* fw2  = (const float*)d_in[15];
  const float* fb2  = (const float*)d_in[16];
  const int* eidx   = (const int*)d_in[17];
  const int* etyp   = (const int*)d_in[18];
  const int* midx   = (const int*)d_in[19];

  const int Nn = in_sizes[0] / DD;     // 16000
  const int E = in_sizes[18];          // 256000

  const int* esrc = eidx;
  const int* edst = eidx + E;

  char* p = (char*)d_ws;
  auto alloc = [&](size_t bytes) -> void* {
    void* r = (void*)p;
    p += (bytes + 255) & ~(size_t)255;
    return r;
  };
  _Float16* QKVSh = (_Float16*)alloc((size_t)Nn * QW * 2);
  unsigned char* kvq = (unsigned char*)alloc((size_t)Nn * 512);
  _Float16* xh    = (_Float16*)alloc((size_t)Nn * DD * 2);
  _Float16* hln0  = (_Float16*)alloc((size_t)Nn * DD * 2);
  _Float16* hln1  = (_Float16*)alloc((size_t)Nn * DD * 2);
  _Float16* h1h   = (_Float16*)alloc((size_t)Nn * DD * 2);
  _Float16* WcatT = (_Float16*)alloc((size_t)QW * DD * 2);
  float*    Wcat  = (float*)alloc((size_t)DD * QW * 4);
  float*    bcat  = (float*)alloc(QW * 4);
  _Float16* epth  = (_Float16*)alloc(2560 * 2);
  _Float16* fw1h  = (_Float16*)alloc((size_t)2 * DD * 512 * 2);
  _Float16* fw2Th = (_Float16*)alloc((size_t)2 * DD * 512 * 2);
  float*    Wf    = (float*)alloc(2 * 128 * 128 * 4);
  _Float16* Wfh   = (_Float16*)alloc(128 * 128 * 2);
  float*    bfv   = (float*)alloc(256 * 4);
  float*    bzero = (float*)alloc(1024 * 4);
  _Float16* BtMid = (_Float16*)alloc((size_t)1024 * 128 * 2);
  float*    bmid  = (float*)alloc(1024 * 4);
  int* offs   = (int*)alloc((size_t)(Nn + 1) * 4);
  int* bbase  = (int*)alloc((NB + 1) * 4);
  int* bcursor= (int*)alloc((NB + 1) * 4);
  int* dcur   = (int*)alloc(64 * 4);
  int* order  = (int*)alloc((size_t)Nn * 4);
  const int nsblk = (E + 2047) / 2048;
  int* bparts = (int*)alloc((size_t)nsblk * 128 * 4);
  int* dparts = (int*)alloc((size_t)NB * 64 * 4);
  unsigned* ebuf = (unsigned*)alloc((size_t)E * 4);
  unsigned* epk  = (unsigned*)alloc((size_t)E * 4);

  // CSR build (no memsets: partial histograms)
  csr_count<<<nsblk, 256, 0, stream>>>(edst, bparts, E);
  csr_scan<<<1, 128, 0, stream>>>(bparts, nsblk, bbase, bcursor, offs, E, Nn);
  csr_scatter<<<nsblk, 256, 0, stream>>>(edst, esrc, etyp, bcursor, ebuf, E);
  csr_fine<<<NB, 256, 0, stream>>>(ebuf, bbase, epk, offs, dparts);
  deg_scan<<<1, 64, 0, stream>>>(dparts, NB, dcur);
  deg_order<<<(Nn + 255) / 256, 256, 0, stream>>>(offs, dcur, order, Nn);

  // Precompute (pp_cast includes fw2 transpose tail blocks)
  const int pc_threads = 256 + 2560 + 114688 + 896 + 1024 + 16384 + Nn * 16;
  const int nb0 = (pc_threads + 255) / 256;
  pp_cast<<<nb0 + 32, 256, 0, stream>>>(
      Wq, Wk, Wv, Wsk, bq, bk, bv, bsk, hemb, We, x, fw1, fb1, fw2, fb2,
      WcatT, Wcat, bcat, epth, xh, fw1h, fw2Th, bfv, bzero, Nn, nb0);
  pp_bmid<<<4, 256, 0, stream>>>(bfv, Wcat, bcat, bmid);
  wf_gemm<<<dim3(1, 1, 2), 256, 0, stream>>>(fw1h, fw2Th, Wf, Wfh, BtMid);
  // BtMid rows 128..1023 = (Wf0 @ Wcat)^T
  gemm_tn_f16<false, false, true><<<dim3(7, 1), 256, 0, stream>>>(
      Wfh, WcatT, bzero, nullptr, 0, nullptr, 0, 0, BtMid + 16384, 128, 128, 896, 128);

  const int kvq_total = Nn * 32;
  // Layer 0: QKVS0 = xh @ Wcat + bcat
  gemm_tn_f16<false, true, false><<<dim3(QW / 128, Nn / 128), 256, 0, stream>>>(
      xh, WcatT, bcat, nullptr, 0, QKVSh, 0, QW, nullptr, 0, Nn, QW, DD);
  kv_quant<<<(kvq_total + 255) / 256, 256, 0, stream>>>(QKVSh, kvq, kvq_total);
  node_attn_ln_kernel<<<Nn / 4, 256, 0, stream>>>(QKVSh, kvq, epth, xh, offs, epk, order,
                                                  lng, lnb, hln0, Nn);
  // Fused: [h1h (f16) | QKVS1 (f16)] = hln0 @ [Wf0 | Wf0@Wcat] + bmid
  gemm_tn_f16<true, true, false><<<dim3(1024 / 128, Nn / 128), 256, 0, stream>>>(
      hln0, BtMid, bmid, h1h, 128, QKVSh, 128, QW, nullptr, 0, Nn, 1024, DD);
  kv_quant<<<(kvq_total + 255) / 256, 256, 0, stream>>>(QKVSh, kvq, kvq_total);
  node_attn_ln_kernel<<<Nn / 4, 256, 0, stream>>>(QKVSh, kvq, epth, h1h, offs, epk, order,
                                                  lng + DD, lnb + DD, hln1, Nn);
  final_kernel<<<64, 128, 0, stream>>>(hln1, Wf, bfv, midx, (float*)d_out);
}

// Round 17
// 246.836 us; speedup vs baseline: 1.0426x; 1.0426x over previous
//
#include <hip/hip_runtime.h>
#include <hip/hip_bf16.h>
#include <math.h>

#define DD 128
#define QW 896       // 256(Q)+256(K)+256(V)+128(skip)
#define NB 125       // coarse buckets (dst>>7), 128 nodes each
#define BCAP 4096

typedef _Float16 f16x8 __attribute__((ext_vector_type(8)));
typedef _Float16 f16x4 __attribute__((ext_vector_type(4)));
typedef _Float16 f16x2 __attribute__((ext_vector_type(2)));
typedef float f32x4 __attribute__((ext_vector_type(4)));
typedef float f32x2 __attribute__((ext_vector_type(2)));

__device__ __forceinline__ float fdot2f(f16x2 a, f16x2 b, float c) {
#if __has_builtin(__builtin_amdgcn_fdot2)
  return __builtin_amdgcn_fdot2(a, b, c, false);
#else
  return fmaf((float)a[0], (float)b[0], fmaf((float)a[1], (float)b[1], c));
#endif
}

// ---- fp8 e4m3 (OCP) helpers: encoder flushes subnormals (|v|<2^-6 -> 0) ----
__device__ __forceinline__ unsigned e4m3b(float v) {
  float a = fabsf(v);
  unsigned s = (__float_as_uint(v) >> 24) & 0x80u;
  if (!(a >= 0.015625f)) return s;
  if (a > 448.f) a = 448.f;
  unsigned u = __float_as_uint(a) + (1u << 19);  // round-half-up into m3
  int e = (int)((u >> 23) & 255) - 120;
  if (e > 15) return s | 0x7Eu;                  // clamp to 448
  return s | ((unsigned)e << 3) | ((u >> 20) & 7u);
}
__device__ __forceinline__ float e4m3f(unsigned b) {
  unsigned em = b & 0x7Fu;
  unsigned s = (b & 0x80u) << 24;
  if (em == 0) return __uint_as_float(s);
  return __uint_as_float(s | (((em >> 3) + 120u) << 23) | ((em & 7u) << 20));
}
template <bool HI>
__device__ __forceinline__ f32x2 fp8x2f(unsigned w) {
#if __has_builtin(__builtin_amdgcn_cvt_pk_f32_fp8)
  return __builtin_amdgcn_cvt_pk_f32_fp8((int)w, HI);
#else
  unsigned h = HI ? (w >> 16) : w;
  f32x2 r; r[0] = e4m3f(h & 255u); r[1] = e4m3f((h >> 8) & 255u);
  return r;
#endif
}

// ---------------- CSR build: two-level LDS counting sort (no memsets) ----------------
__global__ __launch_bounds__(256) void csr_count(const int* __restrict__ edst,
                                                 int* __restrict__ bparts, int E) {
  __shared__ int h[NB];
  const int tid = threadIdx.x;
  if (tid < NB) h[tid] = 0;
  __syncthreads();
  const int e0 = blockIdx.x * 2048;
  for (int k = 0; k < 8; ++k) {
    int e = e0 + k * 256 + tid;
    if (e < E) atomicAdd(&h[edst[e] >> 7], 1);
  }
  __syncthreads();
  if (tid < 128) bparts[blockIdx.x * 128 + tid] = (tid < NB) ? h[tid] : 0;
}

__global__ __launch_bounds__(128) void csr_scan(const int* __restrict__ bparts, int nblk,
                                                int* __restrict__ bbase,
                                                int* __restrict__ bcursor,
                                                int* __restrict__ offs, int E, int Nn) {
  __shared__ int sc[128];
  const int tid = threadIdx.x;
  int s = 0;
  for (int b = 0; b < nblk; ++b) s += bparts[b * 128 + tid];
  sc[tid] = (tid < NB) ? s : 0;
  __syncthreads();
  for (int d = 1; d < 128; d <<= 1) {
    int t = (tid >= d) ? sc[tid - d] : 0;
    __syncthreads();
    sc[tid] += t;
    __syncthreads();
  }
  const int excl = tid ? sc[tid - 1] : 0;
  if (tid < NB) { bbase[tid] = excl; bcursor[tid] = excl; }
  if (tid == 0) { bbase[NB] = E; offs[Nn] = E; }
}

__global__ __launch_bounds__(256) void csr_scatter(const int* __restrict__ edst,
                                                   const int* __restrict__ esrc,
                                                   const int* __restrict__ etyp,
                                                   int* __restrict__ bcursor,
                                                   unsigned* __restrict__ ebuf, int E) {
  __shared__ int h[NB], cur[NB];
  const int tid = threadIdx.x;
  if (tid < NB) h[tid] = 0;
  __syncthreads();
  const int e0 = blockIdx.x * 2048;
  int dd[8];
  for (int k = 0; k < 8; ++k) {
    int e = e0 + k * 256 + tid;
    dd[k] = (e < E) ? edst[e] : -1;
    if (dd[k] >= 0) atomicAdd(&h[dd[k] >> 7], 1);
  }
  __syncthreads();
  if (tid < NB && h[tid]) cur[tid] = atomicAdd(&bcursor[tid], h[tid]);
  __syncthreads();
  for (int k = 0; k < 8; ++k) {
    int e = e0 + k * 256 + tid;
    if (dd[k] >= 0) {
      int pos = atomicAdd(&cur[dd[k] >> 7], 1);
      ebuf[pos] = (unsigned)esrc[e] | ((unsigned)etyp[e] << 14) |
                  ((unsigned)(dd[k] & 127) << 18);
    }
  }
}

__global__ __launch_bounds__(256) void csr_fine(const unsigned* __restrict__ ebuf,
                                                const int* __restrict__ bbase,
                                                unsigned* __restrict__ epk,
                                                int* __restrict__ offs,
                                                int* __restrict__ dparts) {
  __shared__ unsigned sed[BCAP];
  __shared__ unsigned sout[BCAP];
  __shared__ int fh[128], sc[128], fc[128], hb[64];
  const int b = blockIdx.x, tid = threadIdx.x;
  const int base = bbase[b], cnt = bbase[b + 1] - base;
  for (int idx = tid; idx < cnt; idx += 256) sed[idx] = ebuf[base + idx];
  if (tid < 128) fh[tid] = 0;
  if (tid < 64) hb[tid] = 0;
  __syncthreads();
  for (int idx = tid; idx < cnt; idx += 256) atomicAdd(&fh[(sed[idx] >> 18) & 127], 1);
  __syncthreads();
  if (tid < 128) sc[tid] = fh[tid];
  __syncthreads();
  for (int d = 1; d < 128; d <<= 1) {
    int t = (tid < 128 && tid >= d) ? sc[tid - d] : 0;
    __syncthreads();
    if (tid < 128) sc[tid] += t;
    __syncthreads();
  }
  if (tid < 128) {
    const int excl = tid ? sc[tid - 1] : 0;
    offs[b * 128 + tid] = base + excl;
    fc[tid] = excl;
    atomicAdd(&hb[min(fh[tid], 63)], 1);
  }
  __syncthreads();
  if (tid < 64) dparts[b * 64 + tid] = hb[tid];
  for (int idx = tid; idx < cnt; idx += 256) {
    const unsigned v = sed[idx];
    const int pos = atomicAdd(&fc[(v >> 18) & 127], 1);
    sout[pos] = (v & 0x3FFF) | (((v >> 14) & 0xF) << 18);  // src | typ<<18
  }
  __syncthreads();
  for (int idx = tid; idx < cnt; idx += 256) epk[base + idx] = sout[idx];
}

__global__ __launch_bounds__(64) void deg_scan(const int* __restrict__ dparts, int nblk,
                                               int* __restrict__ dcur) {
  __shared__ int tot[64];
  const int t = threadIdx.x;
  int s = 0;
  for (int b = 0; b < nblk; ++b) s += dparts[b * 64 + t];
  tot[t] = s;
  __syncthreads();
  int acc = 0;
  for (int d = t + 1; d < 64; ++d) acc += tot[d];
  dcur[t] = acc;
}

__global__ __launch_bounds__(256) void deg_order(const int* __restrict__ offs,
                                                 int* __restrict__ dcur,
                                                 int* __restrict__ order, int Nn) {
  __shared__ int h[64], cbase[64];
  const int tid = threadIdx.x;
  const int i = blockIdx.x * 256 + tid;
  if (tid < 64) h[tid] = 0;
  __syncthreads();
  int bk = -1;
  if (i < Nn) {
    bk = min(offs[i + 1] - offs[i], 63);
    atomicAdd(&h[bk], 1);
  }
  __syncthreads();
  if (tid < 64) {
    const int c = h[tid];
    cbase[tid] = c ? atomicAdd(&dcur[tid], c) : 0;
    h[tid] = 0;
  }
  __syncthreads();
  if (bk >= 0) {
    const int pos = cbase[bk] + atomicAdd(&h[bk], 1);
    order[pos] = i;
  }
}

// ---------------- pp_cast: all parallel precompute + fw2 transpose tail blocks ------
__global__ __launch_bounds__(256) void pp_cast(
    const float* __restrict__ Wq, const float* __restrict__ Wk,
    const float* __restrict__ Wv, const float* __restrict__ Wsk,
    const float* __restrict__ bq, const float* __restrict__ bk,
    const float* __restrict__ bv, const float* __restrict__ bsk,
    const float* __restrict__ hemb, const float* __restrict__ We,
    const float* __restrict__ x,
    const float* __restrict__ fw1, const float* __restrict__ fb1,
    const float* __restrict__ fw2, const float* __restrict__ fb2,
    _Float16* __restrict__ WcatT, float* __restrict__ Wcat, float* __restrict__ bcat,
    _Float16* __restrict__ epth, _Float16* __restrict__ xh,
    _Float16* __restrict__ fw1h, _Float16* __restrict__ fw2Th,
    float* __restrict__ bfv, float* __restrict__ bzero, int Nn, int nb0) {
  __shared__ _Float16 tile[64][65];
  if (blockIdx.x >= nb0) {  // fw2 transpose+cast tail blocks (32 tiles)
    const int tb = blockIdx.x - nb0;
    const int l = tb >> 4, r2 = tb & 15;
    const int k0 = (r2 >> 1) << 6, j0 = (r2 & 1) << 6;
    const size_t base = (size_t)l * 65536;
    const int tid = threadIdx.x;
    for (int idx = tid; idx < 4096; idx += 256) {
      int rr = idx >> 6, cc = idx & 63;
      tile[rr][cc] = (_Float16)fw2[base + (size_t)(k0 + rr) * 128 + j0 + cc];
    }
    __syncthreads();
    for (int idx = tid; idx < 4096; idx += 256) {
      int rr = idx >> 6, cc = idx & 63;
      fw2Th[base + (size_t)(j0 + rr) * 512 + k0 + cc] = tile[cc][rr];
    }
    return;
  }
  int t = blockIdx.x * 256 + threadIdx.x;
  if (t < 256) {  // bfv[l][j]
    int l = t >> 7, j = t & 127;
    const float* b1 = fb1 + l * 512;
    const float* w2 = fw2 + (size_t)l * 65536 + j;
    float s0 = fb2[l * 128 + j], s1 = 0.f, s2 = 0.f, s3 = 0.f;
    for (int k = 0; k < 512; k += 4) {
      s0 = fmaf(b1[k], w2[(size_t)k * 128], s0);
      s1 = fmaf(b1[k + 1], w2[(size_t)(k + 1) * 128], s1);
      s2 = fmaf(b1[k + 2], w2[(size_t)(k + 2) * 128], s2);
      s3 = fmaf(b1[k + 3], w2[(size_t)(k + 3) * 128], s3);
    }
    bfv[t] = ((s0 + s1) + (s2 + s3));
    return;
  }
  t -= 256;
  if (t < 2560) {  // eproj
    int ty = t >> 8, col = t & 255;
    float s0 = 0.f, s1 = 0.f, s2 = 0.f, s3 = 0.f;
    const float* hr = hemb + ty * 128;
    for (int c = 0; c < 128; c += 4) {
      s0 = fmaf(hr[c], We[c * 256 + col], s0);
      s1 = fmaf(hr[c + 1], We[(c + 1) * 256 + col], s1);
      s2 = fmaf(hr[c + 2], We[(c + 2) * 256 + col], s2);
      s3 = fmaf(hr[c + 3], We[(c + 3) * 256 + col], s3);
    }
    epth[t] = (_Float16)((s0 + s1) + (s2 + s3));
    return;
  }
  t -= 2560;
  if (t < 114688) {  // WcatT f16 [896][128] + Wcat f32 [128][896]
    int n = t >> 7, k = t & 127;
    float v;
    if (n < 256) v = Wq[k * 256 + n];
    else if (n < 512) v = Wk[k * 256 + (n - 256)];
    else if (n < 768) v = Wv[k * 256 + (n - 512)];
    else v = Wsk[k * 128 + (n - 768)];
    WcatT[t] = (_Float16)v;
    Wcat[k * 896 + n] = v;
    return;
  }
  t -= 114688;
  if (t < 896) {
    float v;
    if (t < 256) v = bq[t];
    else if (t < 512) v = bk[t - 256];
    else if (t < 768) v = bv[t - 512];
    else v = bsk[t - 768];
    bcat[t] = v;
    return;
  }
  t -= 896;
  if (t < 1024) { bzero[t] = 0.f; return; }
  t -= 1024;
  if (t < 16384) {  // fw1 cast
    float4 v0 = *reinterpret_cast<const float4*>(fw1 + (size_t)t * 8);
    float4 v1 = *reinterpret_cast<const float4*>(fw1 + (size_t)t * 8 + 4);
    f16x8 o;
    o[0] = (_Float16)v0.x; o[1] = (_Float16)v0.y; o[2] = (_Float16)v0.z; o[3] = (_Float16)v0.w;
    o[4] = (_Float16)v1.x; o[5] = (_Float16)v1.y; o[6] = (_Float16)v1.z; o[7] = (_Float16)v1.w;
    *reinterpret_cast<f16x8*>(fw1h + (size_t)t * 8) = o;
    return;
  }
  t -= 16384;
  if (t < Nn * 16) {  // cast x -> f16
    float4 v0 = *reinterpret_cast<const float4*>(x + (size_t)t * 8);
    float4 v1 = *reinterpret_cast<const float4*>(x + (size_t)t * 8 + 4);
    f16x8 o;
    o[0] = (_Float16)v0.x; o[1] = (_Float16)v0.y; o[2] = (_Float16)v0.z; o[3] = (_Float16)v0.w;
    o[4] = (_Float16)v1.x; o[5] = (_Float16)v1.y; o[6] = (_Float16)v1.z; o[7] = (_Float16)v1.w;
    *reinterpret_cast<f16x8*>(xh + (size_t)t * 8) = o;
  }
}

// ---------------- pp_bmid: bmid = [bfv0 | bfv0@Wcat + bcat] ----------------
__global__ __launch_bounds__(256) void pp_bmid(const float* __restrict__ bfv,
                                               const float* __restrict__ Wcat,
                                               const float* __restrict__ bcat,
                                               float* __restrict__ bmid) {
  int t = blockIdx.x * 256 + threadIdx.x;
  if (t >= 1024) return;
  if (t < 128) { bmid[t] = bfv[t]; return; }
  int n = t - 128;
  float s0 = bcat[n], s1 = 0.f, s2 = 0.f, s3 = 0.f;
  for (int c = 0; c < 128; c += 4) {
    s0 = fmaf(bfv[c], Wcat[c * 896 + n], s0);
    s1 = fmaf(bfv[c + 1], Wcat[(c + 1) * 896 + n], s1);
    s2 = fmaf(bfv[c + 2], Wcat[(c + 2) * 896 + n], s2);
    s3 = fmaf(bfv[c + 3], Wcat[(c + 3) * 896 + n], s3);
  }
  bmid[t] = ((s0 + s1) + (s2 + s3));
}

// ---------------- Wf[z] = fw1h[z] @ fw2Th[z]^T  (grid.z=2) -------------
__global__ __launch_bounds__(256) void wf_gemm(const _Float16* __restrict__ fw1h,
                                               const _Float16* __restrict__ fw2Th,
                                               float* __restrict__ Wf,
                                               _Float16* __restrict__ Wfh,
                                               _Float16* __restrict__ BtMid0) {
  const int z = blockIdx.z;
  const _Float16* A = fw1h + z * 65536;
  const _Float16* Bt = fw2Th + z * 65536;
  const int tid = threadIdx.x;
  const int wid = tid >> 6, lane = tid & 63;
  const int wr = wid >> 1, wc = wid & 1;
  const int il = lane & 15, g = lane >> 4;
  const int row0 = wr * 64, col0 = wc * 64;
  const _Float16* Ap = A + (size_t)(row0 + il) * 512 + 8 * g;
  const _Float16* Bp = Bt + (size_t)(col0 + il) * 512 + 8 * g;
  f32x4 acc[4][4];
#pragma unroll
  for (int a = 0; a < 4; ++a)
#pragma unroll
    for (int b = 0; b < 4; ++b) acc[a][b] = (f32x4){0.f, 0.f, 0.f, 0.f};
  for (int k0 = 0; k0 < 512; k0 += 32) {
    f16x8 af[4], bf[4];
#pragma unroll
    for (int f = 0; f < 4; ++f) {
      af[f] = *reinterpret_cast<const f16x8*>(Ap + (size_t)(f * 16) * 512 + k0);
      bf[f] = *reinterpret_cast<const f16x8*>(Bp + (size_t)(f * 16) * 512 + k0);
    }
#pragma unroll
    for (int fi = 0; fi < 4; ++fi)
#pragma unroll
      for (int fj = 0; fj < 4; ++fj)
        acc[fi][fj] = __builtin_amdgcn_mfma_f32_16x16x32_f16(af[fi], bf[fj], acc[fi][fj], 0, 0, 0);
  }
#pragma unroll
  for (int fj = 0; fj < 4; ++fj) {
    const int col = col0 + fj * 16 + il;
#pragma unroll
    for (int fi = 0; fi < 4; ++fi) {
#pragma unroll
      for (int i = 0; i < 4; ++i) {
        const int row = row0 + fi * 16 + g * 4 + i;
        const float v = acc[fi][fj][i];
        Wf[z * 16384 + row * 128 + col] = v;
        if (z == 0) {
          Wfh[row * 128 + col] = (_Float16)v;
          BtMid0[col * 128 + row] = (_Float16)v;
        }
      }
    }
  }
}

// ---------------- MFMA f16 GEMM (K==128): LDS-staged tiles + XOR swizzle ----------
// HAS_KVQ: channels [256,768) (ch = col - choff) additionally written as fp8 e4m3
// into kvq[node][32][K8|V8] (16B interleaved per 8-channel group); the dead f16
// K/V stores are skipped.
template <bool HAS_CFH, bool HAS_CH, bool HAS_CHT, bool HAS_KVQ>
__global__ __launch_bounds__(256) void gemm_tn_f16(const _Float16* __restrict__ A,
                                                   const _Float16* __restrict__ Bt,
                                                   const float* __restrict__ bias,
                                                   _Float16* __restrict__ Cfh, int NF,
                                                   _Float16* __restrict__ Ch, int choff, int ldh,
                                                   _Float16* __restrict__ ChT, int ldt,
                                                   unsigned char* __restrict__ kvq,
                                                   int M, int N, int K) {
  __shared__ __align__(16) char smA[32768];
  __shared__ __align__(16) char smB[32768];
  const int tid = threadIdx.x;
  const int wid = tid >> 6, lane = tid & 63;
  const int wr = wid >> 1, wc = wid & 1;
  const int il = lane & 15, g = lane >> 4;
  const int row0 = blockIdx.y * 128;
  const int col0 = blockIdx.x * 128;
  {
    const f16x8* Ag = reinterpret_cast<const f16x8*>(A + (size_t)row0 * 128);
    const f16x8* Bg = reinterpret_cast<const f16x8*>(Bt + (size_t)col0 * 128);
#pragma unroll
    for (int it = 0; it < 8; ++it) {
      const int c = it * 256 + tid;
      const int r = c >> 4;
      const int off = r * 256 + (((c & 15) << 4) ^ ((r & 7) << 4));
      f16x8 va = Ag[c];
      f16x8 vb = Bg[c];
      *reinterpret_cast<f16x8*>(smA + off) = va;
      *reinterpret_cast<f16x8*>(smB + off) = vb;
    }
  }
  __syncthreads();
  f32x4 acc[4][4];
#pragma unroll
  for (int a = 0; a < 4; ++a)
#pragma unroll
    for (int b = 0; b < 4; ++b) acc[a][b] = (f32x4){0.f, 0.f, 0.f, 0.f};
#pragma unroll
  for (int ks = 0; ks < 4; ++ks) {
    const int kb = ks * 64 + g * 16;
    f16x8 af[4], bf[4];
#pragma unroll
    for (int f = 0; f < 4; ++f) {
      const int ra = wr * 64 + f * 16 + il;
      const int rb = wc * 64 + f * 16 + il;
      af[f] = *reinterpret_cast<const f16x8*>(smA + ra * 256 + (kb ^ ((ra & 7) << 4)));
      bf[f] = *reinterpret_cast<const f16x8*>(smB + rb * 256 + (kb ^ ((rb & 7) << 4)));
    }
#pragma unroll
    for (int fi = 0; fi < 4; ++fi)
#pragma unroll
      for (int fj = 0; fj < 4; ++fj)
        acc[fi][fj] = __builtin_amdgcn_mfma_f32_16x16x32_f16(bf[fj], af[fi], acc[fi][fj], 0, 0, 0);
  }
#pragma unroll
  for (int fi = 0; fi < 4; ++fi) {
    const int row = row0 + wr * 64 + fi * 16 + il;
#pragma unroll
    for (int fj = 0; fj < 4; ++fj) {
      const int col = col0 + wc * 64 + fj * 16 + g * 4;
      const float4 b4 = *reinterpret_cast<const float4*>(bias + col);
      float v0 = acc[fi][fj][0] + b4.x, v1 = acc[fi][fj][1] + b4.y;
      float v2 = acc[fi][fj][2] + b4.z, v3 = acc[fi][fj][3] + b4.w;
      f16x4 o;
      o[0] = (_Float16)v0; o[1] = (_Float16)v1; o[2] = (_Float16)v2; o[3] = (_Float16)v3;
      const int ch = col - choff;  // channel within QKVS row
      if constexpr (HAS_CFH) {
        if (col < NF) *reinterpret_cast<f16x4*>(&Cfh[(size_t)row * NF + col]) = o;
      }
      if constexpr (HAS_CH) {
        const bool kvrange = HAS_KVQ && (ch >= 256 && ch < 768);
        if (col >= choff && !kvrange)
          *reinterpret_cast<f16x4*>(&Ch[(size_t)row * ldh + ch]) = o;
      }
      if constexpr (HAS_KVQ) {
        if (ch >= 256 && ch < 768) {
          const int c = (ch >= 512) ? (ch - 512) : (ch - 256);
          const int boff = ((c >> 3) << 4) + (c & 7) + ((ch >= 512) ? 8 : 0);
          unsigned pk = e4m3b(v0) | (e4m3b(v1) << 8) | (e4m3b(v2) << 16) | (e4m3b(v3) << 24);
          *reinterpret_cast<unsigned*>(kvq + (size_t)row * 512 + boff) = pk;
        }
      }
      if constexpr (HAS_CHT) {
#pragma unroll
        for (int i = 0; i < 4; ++i) ChT[(size_t)(col + i) * ldt + row] = o[i];
      }
    }
  }
}

// ---------------- fused per-node attention: fp8 K/V gather, single-pass online softmax --
// Per edge sub-slot: ONE 16B load from kvq (lane's K8 fp8 + V8 fp8).
__global__ __launch_bounds__(256) void node_attn_ln_kernel(
    const _Float16* __restrict__ QKVSh, const unsigned char* __restrict__ kvq,
    const _Float16* __restrict__ epth,
    const _Float16* __restrict__ hpre,
    const int* __restrict__ offs, const unsigned* __restrict__ epk,
    const int* __restrict__ order,
    const float* __restrict__ gamma, const float* __restrict__ beta,
    _Float16* __restrict__ hlnh, int Nn) {
  __shared__ float sqe[4][2][10];
  __shared__ __align__(16) _Float16 elds[2560];
  const int tid = threadIdx.x;
  for (int t = tid; t < 1280; t += 256)
    reinterpret_cast<unsigned*>(elds)[t] = reinterpret_cast<const unsigned*>(epth)[t];
  __syncthreads();
  const int w = tid >> 6, lane = tid & 63;
  const int i = order[blockIdx.x * 4 + w];
  const int sub = lane >> 5;
  const int r = lane & 31;
  const int half = r >> 4;
  const int co = r << 3;
  const float scale = 0.08838834764831845f;  // 1/sqrt(128)
  f16x8 qh = *reinterpret_cast<const f16x8*>(QKVSh + (size_t)i * QW + co);
  const f16x2* q2 = reinterpret_cast<const f16x2*>(&qh);
  float qf[8];
#pragma unroll
  for (int t = 0; t < 8; ++t) qf[t] = (float)qh[t] * scale;
#pragma unroll
  for (int ty = 0; ty < 10; ++ty) {
    f16x8 ev = *reinterpret_cast<const f16x8*>(elds + (ty << 8) + co);
    const f16x2* e2 = reinterpret_cast<const f16x2*>(&ev);
    float s = 0.f;
#pragma unroll
    for (int p2 = 0; p2 < 4; ++p2) s = fdot2f(q2[p2], e2[p2], s);
    s += __shfl_xor(s, 1); s += __shfl_xor(s, 2);
    s += __shfl_xor(s, 4); s += __shfl_xor(s, 8);
    if (lane < 32 && (r & 15) == 0) sqe[w][half][ty] = s * scale;
  }
  __threadfence_block();
  float m_me = -1e30f, s_me = 0.f;
  float acc[8] = {0.f};
  const int ebeg = offs[i], eend = offs[i + 1];
  if (ebeg < eend) {
    const int last = eend - 1;
    unsigned pk0 = epk[min(ebeg + sub, last)];
    unsigned pk1 = epk[min(ebeg + 2 + sub, last)];
    uint4 kv0 = *reinterpret_cast<const uint4*>(kvq + (size_t)(pk0 & 0x3FFFF) * 512 + (r << 4));
    uint4 kv1 = *reinterpret_cast<const uint4*>(kvq + (size_t)(pk1 & 0x3FFFF) * 512 + (r << 4));
    for (int j = ebeg; j < eend; j += 2) {
      const uint4 cur = kv0;
      const unsigned pkc = pk0;
      kv0 = kv1; pk0 = pk1;
      pk1 = epk[min(j + 4 + sub, last)];
      kv1 = *reinterpret_cast<const uint4*>(kvq + (size_t)(pk1 & 0x3FFFF) * 512 + (r << 4));
      const int tyc = pkc >> 18;
      // decode K (8 fp8 in cur.x, cur.y), dot with pre-scaled qf
      f32x2 k0 = fp8x2f<false>(cur.x), k1 = fp8x2f<true>(cur.x);
      f32x2 k2 = fp8x2f<false>(cur.y), k3 = fp8x2f<true>(cur.y);
      float d = qf[0] * k0[0];
      d = fmaf(qf[1], k0[1], d); d = fmaf(qf[2], k1[0], d); d = fmaf(qf[3], k1[1], d);
      d = fmaf(qf[4], k2[0], d); d = fmaf(qf[5], k2[1], d);
      d = fmaf(qf[6], k3[0], d); d = fmaf(qf[7], k3[1], d);
      d += __shfl_xor(d, 1); d += __shfl_xor(d, 2);
      d += __shfl_xor(d, 4); d += __shfl_xor(d, 8);
      d += sqe[w][half][tyc];
      float e;
      if (d > m_me + 8.f) {  // defer-max: fires ~once per node
        const float rr = __expf(m_me - d);
        s_me *= rr;
#pragma unroll
        for (int t = 0; t < 8; ++t) acc[t] *= rr;
        m_me = d;
        e = 1.f;
      } else {
        e = __expf(d - m_me);
      }
      if (j + sub >= eend) e = 0.f;  // odd-tail mask
      s_me += e;
      // decode V (cur.z, cur.w); acc += (v + ept)*e
      f32x2 v0 = fp8x2f<false>(cur.z), v1 = fp8x2f<true>(cur.z);
      f32x2 v2 = fp8x2f<false>(cur.w), v3 = fp8x2f<true>(cur.w);
      f16x8 ec = *reinterpret_cast<const f16x8*>(elds + (tyc << 8) + co);
      acc[0] = fmaf(v0[0], e, acc[0]); acc[1] = fmaf(v0[1], e, acc[1]);
      acc[2] = fmaf(v1[0], e, acc[2]); acc[3] = fmaf(v1[1], e, acc[3]);
      acc[4] = fmaf(v2[0], e, acc[4]); acc[5] = fmaf(v2[1], e, acc[5]);
      acc[6] = fmaf(v3[0], e, acc[6]); acc[7] = fmaf(v3[1], e, acc[7]);
#pragma unroll
      for (int t = 0; t < 8; ++t) acc[t] = fmaf((float)ec[t], e, acc[t]);
    }
  }
  // merge the two edge slots (lane^32 holds same (half, co))
  const float mo = __shfl_xor(m_me, 32);
  const float so = __shfl_xor(s_me, 32);
  const float mf = fmaxf(m_me, mo);
  const float sc_me = __expf(m_me - mf);
  const float sc_o = __expf(mo - mf);
  const float s_tot = s_me * sc_me + so * sc_o;
  const float invme = 1.f / (s_tot + 1e-16f);
  float g[8];
#pragma unroll
  for (int t = 0; t < 8; ++t) {
    const float ao = __shfl_xor(acc[t], 32);
    const float a = (acc[t] * sc_me + ao * sc_o) * invme;
    g[t] = 0.5f * (a + __shfl_xor(a, 16));  // head mean
  }
  const int cm = (r & 15) << 3;
  f16x8 sk = *reinterpret_cast<const f16x8*>(QKVSh + (size_t)i * QW + 768 + cm);
  f16x8 pr = *reinterpret_cast<const f16x8*>(hpre + (size_t)i * DD + cm);
  float xv[8];
#pragma unroll
  for (int t = 0; t < 8; ++t) xv[t] = g[t] + (float)sk[t] + (float)pr[t];
  float sm = 0.f;
#pragma unroll
  for (int t = 0; t < 8; ++t) sm += xv[t];
  sm += __shfl_xor(sm, 1); sm += __shfl_xor(sm, 2);
  sm += __shfl_xor(sm, 4); sm += __shfl_xor(sm, 8);
  const float mu = sm * (1.f / 128.f);
  float dx[8], vvs = 0.f;
#pragma unroll
  for (int t = 0; t < 8; ++t) { dx[t] = xv[t] - mu; vvs += dx[t] * dx[t]; }
  vvs += __shfl_xor(vvs, 1); vvs += __shfl_xor(vvs, 2);
  vvs += __shfl_xor(vvs, 4); vvs += __shfl_xor(vvs, 8);
  const float rstd = rsqrtf(vvs * (1.f / 128.f) + 1e-6f);
  if (lane < 16) {
    float4 gm0 = *reinterpret_cast<const float4*>(gamma + cm);
    float4 gm1 = *reinterpret_cast<const float4*>(gamma + cm + 4);
    float4 bt0 = *reinterpret_cast<const float4*>(beta + cm);
    float4 bt1 = *reinterpret_cast<const float4*>(beta + cm + 4);
    f16x8 o;
    o[0] = (_Float16)(dx[0] * rstd * gm0.x + bt0.x);
    o[1] = (_Float16)(dx[1] * rstd * gm0.y + bt0.y);
    o[2] = (_Float16)(dx[2] * rstd * gm0.z + bt0.z);
    o[3] = (_Float16)(dx[3] * rstd * gm0.w + bt0.w);
    o[4] = (_Float16)(dx[4] * rstd * gm1.x + bt1.x);
    o[5] = (_Float16)(dx[5] * rstd * gm1.y + bt1.y);
    o[6] = (_Float16)(dx[6] * rstd * gm1.z + bt1.z);
    o[7] = (_Float16)(dx[7] * rstd * gm1.w + bt1.w);
    *reinterpret_cast<f16x8*>(hlnh + (size_t)i * DD + cm) = o;
  }
}

// ---------------- final: gather mask rows of hln1, apply layer-1 fused FFN ----------------
__global__ __launch_bounds__(128) void final_kernel(const _Float16* __restrict__ hlnh1,
                                                    const float* __restrict__ Wf,
                                                    const float* __restrict__ bfv,
                                                    const int* __restrict__ midx,
                                                    float* __restrict__ out) {
  __shared__ float rowv[128];
  const int b = blockIdx.x, j = threadIdx.x;
  const int row = midx[b];
  rowv[j] = (float)hlnh1[(size_t)row * DD + j];
  __syncthreads();
  const float* w1 = Wf + 16384 + j;
  float s = bfv[128 + j];
#pragma unroll 4
  for (int c = 0; c < 128; ++c) s = fmaf(rowv[c], w1[c * 128], s);
  out[b * DD + j] = s;
}

extern "C" void kernel_launch(void* const* d_in, const int* in_sizes, int n_in,
                              void* d_out, int out_size, void* d_ws, size_t ws_size,
                              hipStream_t stream) {
  const float* x    = (const float*)d_in[0];
  const float* hemb = (const float*)d_in[1];
  const float* Wq   = (const float*)d_in[2];
  const float* bq   = (const float*)d_in[3];
  const float* Wk   = (const float*)d_in[4];
  const float* bk   = (const float*)d_in[5];
  const float* Wv   = (const float*)d_in[6];
  const float* bv   = (const float*)d_in[7];
  const float* We   = (const float*)d_in[8];
  const float* Wsk  = (const float*)d_in[9];
  const float* bsk  = (const float*)d_in[10];
  const float* lng  = (const float*)d_in[11];
  const float* lnb  = (const float*)d_in[12];
  const float* fw1  = (const float*)d_in[13];
  const float* fb1  = (const float*)d_in[14];
  const float* fw2  = (const float*)d_in[15];
  const float* fb2  = (const float*)d_in[16];
  const int* eidx   = (const int*)d_in[17];
  const int* etyp   = (const int*)d_in[18];
  const int* midx   = (const int*)d_in[19];

  const int Nn = in_sizes[0] / DD;     // 16000
  const int E = in_sizes[18];          // 256000

  const int* esrc = eidx;
  const int* edst = eidx + E;

  char* p = (char*)d_ws;
  auto alloc = [&](size_t bytes) -> void* {
    void* r = (void*)p;
    p += (bytes + 255) & ~(size_t)255;
    return r;
  };
  _Float16* QKVSh = (_Float16*)alloc((size_t)Nn * QW * 2);
  unsigned char* kvq = (unsigned char*)alloc((size_t)Nn * 512);
  _Float16* xh    = (_Float16*)alloc((size_t)Nn * DD * 2);
  _Float16* hln0  = (_Float16*)alloc((size_t)Nn * DD * 2);
  _Float16* hln1  = (_Float16*)alloc((size_t)Nn * DD * 2);
  _Float16* h1h   = (_Float16*)alloc((size_t)Nn * DD * 2);
  _Float16* WcatT = (_Float16*)alloc((size_t)QW * DD * 2);
  float*    Wcat  = (float*)alloc((size_t)DD * QW * 4);
  float*    bcat  = (float*)alloc(QW * 4);
  _Float16* epth  = (_Float16*)alloc(2560 * 2);
  _Float16* fw1h  = (_Float16*)alloc((size_t)2 * DD * 512 * 2);
  _Float16* fw2Th = (_Float16*)alloc((size_t)2 * DD * 512 * 2);
  float*    Wf    = (float*)alloc(2 * 128 * 128 * 4);
  _Float16* Wfh   = (_Float16*)alloc(128 * 128 * 2);
  float*    bfv   = (float*)alloc(256 * 4);
  float*    bzero = (float*)alloc(1024 * 4);
  _Float16* BtMid = (_Float16*)alloc((size_t)1024 * 128 * 2);
  float*    bmid  = (float*)alloc(1024 * 4);
  int* offs   = (int*)alloc((size_t)(Nn + 1) * 4);
  int* bbase  = (int*)alloc((NB + 1) * 4);
  int* bcursor= (int*)alloc((NB + 1) * 4);
  int* dcur   = (int*)alloc(64 * 4);
  int* order  = (int*)alloc((size_t)Nn * 4);
  const int nsblk = (E + 2047) / 2048;
  int* bparts = (int*)alloc((size_t)nsblk * 128 * 4);
  int* dparts = (int*)alloc((size_t)NB * 64 * 4);
  unsigned* ebuf = (unsigned*)alloc((size_t)E * 4);
  unsigned* epk  = (unsigned*)alloc((size_t)E * 4);

  // CSR build (no memsets: partial histograms)
  csr_count<<<nsblk, 256, 0, stream>>>(edst, bparts, E);
  csr_scan<<<1, 128, 0, stream>>>(bparts, nsblk, bbase, bcursor, offs, E, Nn);
  csr_scatter<<<nsblk, 256, 0, stream>>>(edst, esrc, etyp, bcursor, ebuf, E);
  csr_fine<<<NB, 256, 0, stream>>>(ebuf, bbase, epk, offs, dparts);
  deg_scan<<<1, 64, 0, stream>>>(dparts, NB, dcur);
  deg_order<<<(Nn + 255) / 256, 256, 0, stream>>>(offs, dcur, order, Nn);

  // Precompute (pp_cast includes fw2 transpose tail blocks)
  const int pc_threads = 256 + 2560 + 114688 + 896 + 1024 + 16384 + Nn * 16;
  const int nb0 = (pc_threads + 255) / 256;
  pp_cast<<<nb0 + 32, 256, 0, stream>>>(
      Wq, Wk, Wv, Wsk, bq, bk, bv, bsk, hemb, We, x, fw1, fb1, fw2, fb2,
      WcatT, Wcat, bcat, epth, xh, fw1h, fw2Th, bfv, bzero, Nn, nb0);
  pp_bmid<<<4, 256, 0, stream>>>(bfv, Wcat, bcat, bmid);
  wf_gemm<<<dim3(1, 1, 2), 256, 0, stream>>>(fw1h, fw2Th, Wf, Wfh, BtMid);
  // BtMid rows 128..1023 = (Wf0 @ Wcat)^T
  gemm_tn_f16<false, false, true, false><<<dim3(7, 1), 256, 0, stream>>>(
      Wfh, WcatT, bzero, nullptr, 0, nullptr, 0, 0, BtMid + 16384, 128, nullptr,
      128, 896, 128);

  // Layer 0: QKVS0 = xh @ Wcat + bcat (K/V also emitted as fp8 kvq)
  gemm_tn_f16<false, true, false, true><<<dim3(QW / 128, Nn / 128), 256, 0, stream>>>(
      xh, WcatT, bcat, nullptr, 0, QKVSh, 0, QW, nullptr, 0, kvq, Nn, QW, DD);
  node_attn_ln_kernel<<<Nn / 4, 256, 0, stream>>>(QKVSh, kvq, epth, xh, offs, epk, order,
                                                  lng, lnb, hln0, Nn);
  // Fused: [h1h (f16) | QKVS1 (f16) + kvq fp8] = hln0 @ [Wf0 | Wf0@Wcat] + bmid
  gemm_tn_f16<true, true, false, true><<<dim3(1024 / 128, Nn / 128), 256, 0, stream>>>(
      hln0, BtMid, bmid, h1h, 128, QKVSh, 128, QW, nullptr, 0, kvq, Nn, 1024, DD);
  node_attn_ln_kernel<<<Nn / 4, 256, 0, stream>>>(QKVSh, kvq, epth, h1h, offs, epk, order,
                                                  lng + DD, lnb + DD, hln1, Nn);
  final_kernel<<<64, 128, 0, stream>>>(hln1, Wf, bfv, midx, (float*)d_out);
}

// Round 18
// 231.876 us; speedup vs baseline: 1.1099x; 1.0645x over previous
//
#include <hip/hip_runtime.h>
#include <hip/hip_bf16.h>
#include <math.h>

#define DD 128
#define QW 896       // 256(Q)+256(K)+256(V)+128(skip)
#define NB 125       // coarse buckets (dst>>7), 128 nodes each
#define BCAP 4096

typedef _Float16 f16x8 __attribute__((ext_vector_type(8)));
typedef _Float16 f16x4 __attribute__((ext_vector_type(4)));
typedef _Float16 f16x2 __attribute__((ext_vector_type(2)));
typedef float f32x4 __attribute__((ext_vector_type(4)));
typedef float f32x2 __attribute__((ext_vector_type(2)));

__device__ __forceinline__ float fdot2f(f16x2 a, f16x2 b, float c) {
#if __has_builtin(__builtin_amdgcn_fdot2)
  return __builtin_amdgcn_fdot2(a, b, c, false);
#else
  return fmaf((float)a[0], (float)b[0], fmaf((float)a[1], (float)b[1], c));
#endif
}

// ---- fp8 e4m3 (OCP) helpers ----
__device__ __forceinline__ unsigned e4m3b(float v) {  // software fallback encoder
  float a = fabsf(v);
  unsigned s = (__float_as_uint(v) >> 24) & 0x80u;
  if (!(a >= 0.015625f)) return s;
  if (a > 448.f) a = 448.f;
  unsigned u = __float_as_uint(a) + (1u << 19);
  int e = (int)((u >> 23) & 255) - 120;
  if (e > 15) return s | 0x7Eu;
  return s | ((unsigned)e << 3) | ((u >> 20) & 7u);
}
__device__ __forceinline__ float e4m3f(unsigned b) {
  unsigned em = b & 0x7Fu;
  unsigned s = (b & 0x80u) << 24;
  if (em == 0) return __uint_as_float(s);
  return __uint_as_float(s | (((em >> 3) + 120u) << 23) | ((em & 7u) << 20));
}
template <bool HI>
__device__ __forceinline__ f32x2 fp8x2f(unsigned w) {
#if __has_builtin(__builtin_amdgcn_cvt_pk_f32_fp8)
  return __builtin_amdgcn_cvt_pk_f32_fp8((int)w, HI);
#else
  unsigned h = HI ? (w >> 16) : w;
  f32x2 r; r[0] = e4m3f(h & 255u); r[1] = e4m3f((h >> 8) & 255u);
  return r;
#endif
}
// hardware pack: 2 f32 -> 2 fp8 bytes into the selected half of `old`
template <bool HI>
__device__ __forceinline__ unsigned cvt2fp8(unsigned old, float a, float b) {
#if __has_builtin(__builtin_amdgcn_cvt_pk_fp8_f32)
  return (unsigned)__builtin_amdgcn_cvt_pk_fp8_f32(a, b, (int)old, HI);
#else
  unsigned pk = e4m3b(a) | (e4m3b(b) << 8);
  return HI ? ((old & 0x0000FFFFu) | (pk << 16)) : ((old & 0xFFFF0000u) | pk);
#endif
}

// ---------------- CSR build: two-level LDS counting sort (no memsets) ----------------
__global__ __launch_bounds__(256) void csr_count(const int* __restrict__ edst,
                                                 int* __restrict__ bparts, int E) {
  __shared__ int h[NB];
  const int tid = threadIdx.x;
  if (tid < NB) h[tid] = 0;
  __syncthreads();
  const int e0 = blockIdx.x * 2048;
  for (int k = 0; k < 8; ++k) {
    int e = e0 + k * 256 + tid;
    if (e < E) atomicAdd(&h[edst[e] >> 7], 1);
  }
  __syncthreads();
  if (tid < 128) bparts[blockIdx.x * 128 + tid] = (tid < NB) ? h[tid] : 0;
}

__global__ __launch_bounds__(128) void csr_scan(const int* __restrict__ bparts, int nblk,
                                                int* __restrict__ bbase,
                                                int* __restrict__ bcursor,
                                                int* __restrict__ offs, int E, int Nn) {
  __shared__ int sc[128];
  const int tid = threadIdx.x;
  int s = 0;
  for (int b = 0; b < nblk; ++b) s += bparts[b * 128 + tid];
  sc[tid] = (tid < NB) ? s : 0;
  __syncthreads();
  for (int d = 1; d < 128; d <<= 1) {
    int t = (tid >= d) ? sc[tid - d] : 0;
    __syncthreads();
    sc[tid] += t;
    __syncthreads();
  }
  const int excl = tid ? sc[tid - 1] : 0;
  if (tid < NB) { bbase[tid] = excl; bcursor[tid] = excl; }
  if (tid == 0) { bbase[NB] = E; offs[Nn] = E; }
}

__global__ __launch_bounds__(256) void csr_scatter(const int* __restrict__ edst,
                                                   const int* __restrict__ esrc,
                                                   const int* __restrict__ etyp,
                                                   int* __restrict__ bcursor,
                                                   unsigned* __restrict__ ebuf, int E) {
  __shared__ int h[NB], cur[NB];
  const int tid = threadIdx.x;
  if (tid < NB) h[tid] = 0;
  __syncthreads();
  const int e0 = blockIdx.x * 2048;
  int dd[8];
  for (int k = 0; k < 8; ++k) {
    int e = e0 + k * 256 + tid;
    dd[k] = (e < E) ? edst[e] : -1;
    if (dd[k] >= 0) atomicAdd(&h[dd[k] >> 7], 1);
  }
  __syncthreads();
  if (tid < NB && h[tid]) cur[tid] = atomicAdd(&bcursor[tid], h[tid]);
  __syncthreads();
  for (int k = 0; k < 8; ++k) {
    int e = e0 + k * 256 + tid;
    if (dd[k] >= 0) {
      int pos = atomicAdd(&cur[dd[k] >> 7], 1);
      ebuf[pos] = (unsigned)esrc[e] | ((unsigned)etyp[e] << 14) |
                  ((unsigned)(dd[k] & 127) << 18);
    }
  }
}

__global__ __launch_bounds__(256) void csr_fine(const unsigned* __restrict__ ebuf,
                                                const int* __restrict__ bbase,
                                                unsigned* __restrict__ epk,
                                                int* __restrict__ offs,
                                                int* __restrict__ dparts) {
  __shared__ unsigned sed[BCAP];
  __shared__ unsigned sout[BCAP];
  __shared__ int fh[128], sc[128], fc[128], hb[64];
  const int b = blockIdx.x, tid = threadIdx.x;
  const int base = bbase[b], cnt = bbase[b + 1] - base;
  for (int idx = tid; idx < cnt; idx += 256) sed[idx] = ebuf[base + idx];
  if (tid < 128) fh[tid] = 0;
  if (tid < 64) hb[tid] = 0;
  __syncthreads();
  for (int idx = tid; idx < cnt; idx += 256) atomicAdd(&fh[(sed[idx] >> 18) & 127], 1);
  __syncthreads();
  if (tid < 128) sc[tid] = fh[tid];
  __syncthreads();
  for (int d = 1; d < 128; d <<= 1) {
    int t = (tid < 128 && tid >= d) ? sc[tid - d] : 0;
    __syncthreads();
    if (tid < 128) sc[tid] += t;
    __syncthreads();
  }
  if (tid < 128) {
    const int excl = tid ? sc[tid - 1] : 0;
    offs[b * 128 + tid] = base + excl;
    fc[tid] = excl;
    atomicAdd(&hb[min(fh[tid], 63)], 1);
  }
  __syncthreads();
  if (tid < 64) dparts[b * 64 + tid] = hb[tid];
  for (int idx = tid; idx < cnt; idx += 256) {
    const unsigned v = sed[idx];
    const int pos = atomicAdd(&fc[(v >> 18) & 127], 1);
    sout[pos] = (v & 0x3FFF) | (((v >> 14) & 0xF) << 18);  // src | typ<<18
  }
  __syncthreads();
  for (int idx = tid; idx < cnt; idx += 256) epk[base + idx] = sout[idx];
}

__global__ __launch_bounds__(64) void deg_scan(const int* __restrict__ dparts, int nblk,
                                               int* __restrict__ dcur) {
  __shared__ int tot[64];
  const int t = threadIdx.x;
  int s = 0;
  for (int b = 0; b < nblk; ++b) s += dparts[b * 64 + t];
  tot[t] = s;
  __syncthreads();
  int acc = 0;
  for (int d = t + 1; d < 64; ++d) acc += tot[d];
  dcur[t] = acc;
}

__global__ __launch_bounds__(256) void deg_order(const int* __restrict__ offs,
                                                 int* __restrict__ dcur,
                                                 int* __restrict__ order, int Nn) {
  __shared__ int h[64], cbase[64];
  const int tid = threadIdx.x;
  const int i = blockIdx.x * 256 + tid;
  if (tid < 64) h[tid] = 0;
  __syncthreads();
  int bk = -1;
  if (i < Nn) {
    bk = min(offs[i + 1] - offs[i], 63);
    atomicAdd(&h[bk], 1);
  }
  __syncthreads();
  if (tid < 64) {
    const int c = h[tid];
    cbase[tid] = c ? atomicAdd(&dcur[tid], c) : 0;
    h[tid] = 0;
  }
  __syncthreads();
  if (bk >= 0) {
    const int pos = cbase[bk] + atomicAdd(&h[bk], 1);
    order[pos] = i;
  }
}

// ---------------- pp_cast: all parallel precompute + fw2 transpose tail blocks ------
__global__ __launch_bounds__(256) void pp_cast(
    const float* __restrict__ Wq, const float* __restrict__ Wk,
    const float* __restrict__ Wv, const float* __restrict__ Wsk,
    const float* __restrict__ bq, const float* __restrict__ bk,
    const float* __restrict__ bv, const float* __restrict__ bsk,
    const float* __restrict__ hemb, const float* __restrict__ We,
    const float* __restrict__ x,
    const float* __restrict__ fw1, const float* __restrict__ fb1,
    const float* __restrict__ fw2, const float* __restrict__ fb2,
    _Float16* __restrict__ WcatT, float* __restrict__ Wcat, float* __restrict__ bcat,
    _Float16* __restrict__ epth, _Float16* __restrict__ xh,
    _Float16* __restrict__ fw1h, _Float16* __restrict__ fw2Th,
    float* __restrict__ bfv, float* __restrict__ bzero, int Nn, int nb0) {
  __shared__ _Float16 tile[64][65];
  if (blockIdx.x >= nb0) {  // fw2 transpose+cast tail blocks (32 tiles)
    const int tb = blockIdx.x - nb0;
    const int l = tb >> 4, r2 = tb & 15;
    const int k0 = (r2 >> 1) << 6, j0 = (r2 & 1) << 6;
    const size_t base = (size_t)l * 65536;
    const int tid = threadIdx.x;
    for (int idx = tid; idx < 4096; idx += 256) {
      int rr = idx >> 6, cc = idx & 63;
      tile[rr][cc] = (_Float16)fw2[base + (size_t)(k0 + rr) * 128 + j0 + cc];
    }
    __syncthreads();
    for (int idx = tid; idx < 4096; idx += 256) {
      int rr = idx >> 6, cc = idx & 63;
      fw2Th[base + (size_t)(j0 + rr) * 512 + k0 + cc] = tile[cc][rr];
    }
    return;
  }
  int t = blockIdx.x * 256 + threadIdx.x;
  if (t < 256) {  // bfv[l][j]
    int l = t >> 7, j = t & 127;
    const float* b1 = fb1 + l * 512;
    const float* w2 = fw2 + (size_t)l * 65536 + j;
    float s0 = fb2[l * 128 + j], s1 = 0.f, s2 = 0.f, s3 = 0.f;
    for (int k = 0; k < 512; k += 4) {
      s0 = fmaf(b1[k], w2[(size_t)k * 128], s0);
      s1 = fmaf(b1[k + 1], w2[(size_t)(k + 1) * 128], s1);
      s2 = fmaf(b1[k + 2], w2[(size_t)(k + 2) * 128], s2);
      s3 = fmaf(b1[k + 3], w2[(size_t)(k + 3) * 128], s3);
    }
    bfv[t] = ((s0 + s1) + (s2 + s3));
    return;
  }
  t -= 256;
  if (t < 2560) {  // eproj
    int ty = t >> 8, col = t & 255;
    float s0 = 0.f, s1 = 0.f, s2 = 0.f, s3 = 0.f;
    const float* hr = hemb + ty * 128;
    for (int c = 0; c < 128; c += 4) {
      s0 = fmaf(hr[c], We[c * 256 + col], s0);
      s1 = fmaf(hr[c + 1], We[(c + 1) * 256 + col], s1);
      s2 = fmaf(hr[c + 2], We[(c + 2) * 256 + col], s2);
      s3 = fmaf(hr[c + 3], We[(c + 3) * 256 + col], s3);
    }
    epth[t] = (_Float16)((s0 + s1) + (s2 + s3));
    return;
  }
  t -= 2560;
  if (t < 114688) {  // WcatT f16 [896][128] + Wcat f32 [128][896]
    int n = t >> 7, k = t & 127;
    float v;
    if (n < 256) v = Wq[k * 256 + n];
    else if (n < 512) v = Wk[k * 256 + (n - 256)];
    else if (n < 768) v = Wv[k * 256 + (n - 512)];
    else v = Wsk[k * 128 + (n - 768)];
    WcatT[t] = (_Float16)v;
    Wcat[k * 896 + n] = v;
    return;
  }
  t -= 114688;
  if (t < 896) {
    float v;
    if (t < 256) v = bq[t];
    else if (t < 512) v = bk[t - 256];
    else if (t < 768) v = bv[t - 512];
    else v = bsk[t - 768];
    bcat[t] = v;
    return;
  }
  t -= 896;
  if (t < 1024) { bzero[t] = 0.f; return; }
  t -= 1024;
  if (t < 16384) {  // fw1 cast
    float4 v0 = *reinterpret_cast<const float4*>(fw1 + (size_t)t * 8);
    float4 v1 = *reinterpret_cast<const float4*>(fw1 + (size_t)t * 8 + 4);
    f16x8 o;
    o[0] = (_Float16)v0.x; o[1] = (_Float16)v0.y; o[2] = (_Float16)v0.z; o[3] = (_Float16)v0.w;
    o[4] = (_Float16)v1.x; o[5] = (_Float16)v1.y; o[6] = (_Float16)v1.z; o[7] = (_Float16)v1.w;
    *reinterpret_cast<f16x8*>(fw1h + (size_t)t * 8) = o;
    return;
  }
  t -= 16384;
  if (t < Nn * 16) {  // cast x -> f16
    float4 v0 = *reinterpret_cast<const float4*>(x + (size_t)t * 8);
    float4 v1 = *reinterpret_cast<const float4*>(x + (size_t)t * 8 + 4);
    f16x8 o;
    o[0] = (_Float16)v0.x; o[1] = (_Float16)v0.y; o[2] = (_Float16)v0.z; o[3] = (_Float16)v0.w;
    o[4] = (_Float16)v1.x; o[5] = (_Float16)v1.y; o[6] = (_Float16)v1.z; o[7] = (_Float16)v1.w;
    *reinterpret_cast<f16x8*>(xh + (size_t)t * 8) = o;
  }
}

// ---------------- pp_bmid: bmid = [bfv0 | bfv0@Wcat + bcat] ----------------
__global__ __launch_bounds__(256) void pp_bmid(const float* __restrict__ bfv,
                                               const float* __restrict__ Wcat,
                                               const float* __restrict__ bcat,
                                               float* __restrict__ bmid) {
  int t = blockIdx.x * 256 + threadIdx.x;
  if (t >= 1024) return;
  if (t < 128) { bmid[t] = bfv[t]; return; }
  int n = t - 128;
  float s0 = bcat[n], s1 = 0.f, s2 = 0.f, s3 = 0.f;
  for (int c = 0; c < 128; c += 4) {
    s0 = fmaf(bfv[c], Wcat[c * 896 + n], s0);
    s1 = fmaf(bfv[c + 1], Wcat[(c + 1) * 896 + n], s1);
    s2 = fmaf(bfv[c + 2], Wcat[(c + 2) * 896 + n], s2);
    s3 = fmaf(bfv[c + 3], Wcat[(c + 3) * 896 + n], s3);
  }
  bmid[t] = ((s0 + s1) + (s2 + s3));
}

// ---------------- Wf[z] = fw1h[z] @ fw2Th[z]^T  (grid.z=2) -------------
__global__ __launch_bounds__(256) void wf_gemm(const _Float16* __restrict__ fw1h,
                                               const _Float16* __restrict__ fw2Th,
                                               float* __restrict__ Wf,
                                               _Float16* __restrict__ Wfh,
                                               _Float16* __restrict__ BtMid0) {
  const int z = blockIdx.z;
  const _Float16* A = fw1h + z * 65536;
  const _Float16* Bt = fw2Th + z * 65536;
  const int tid = threadIdx.x;
  const int wid = tid >> 6, lane = tid & 63;
  const int wr = wid >> 1, wc = wid & 1;
  const int il = lane & 15, g = lane >> 4;
  const int row0 = wr * 64, col0 = wc * 64;
  const _Float16* Ap = A + (size_t)(row0 + il) * 512 + 8 * g;
  const _Float16* Bp = Bt + (size_t)(col0 + il) * 512 + 8 * g;
  f32x4 acc[4][4];
#pragma unroll
  for (int a = 0; a < 4; ++a)
#pragma unroll
    for (int b = 0; b < 4; ++b) acc[a][b] = (f32x4){0.f, 0.f, 0.f, 0.f};
  for (int k0 = 0; k0 < 512; k0 += 32) {
    f16x8 af[4], bf[4];
#pragma unroll
    for (int f = 0; f < 4; ++f) {
      af[f] = *reinterpret_cast<const f16x8*>(Ap + (size_t)(f * 16) * 512 + k0);
      bf[f] = *reinterpret_cast<const f16x8*>(Bp + (size_t)(f * 16) * 512 + k0);
    }
#pragma unroll
    for (int fi = 0; fi < 4; ++fi)
#pragma unroll
      for (int fj = 0; fj < 4; ++fj)
        acc[fi][fj] = __builtin_amdgcn_mfma_f32_16x16x32_f16(af[fi], bf[fj], acc[fi][fj], 0, 0, 0);
  }
#pragma unroll
  for (int fj = 0; fj < 4; ++fj) {
    const int col = col0 + fj * 16 + il;
#pragma unroll
    for (int fi = 0; fi < 4; ++fi) {
#pragma unroll
      for (int i = 0; i < 4; ++i) {
        const int row = row0 + fi * 16 + g * 4 + i;
        const float v = acc[fi][fj][i];
        Wf[z * 16384 + row * 128 + col] = v;
        if (z == 0) {
          Wfh[row * 128 + col] = (_Float16)v;
          BtMid0[col * 128 + row] = (_Float16)v;
        }
      }
    }
  }
}

// ---------------- MFMA f16 GEMM (K==128): LDS-staged tiles + XOR swizzle ----------
// HAS_KVQ: channels [256,768) (ch = col - choff) additionally written as fp8 e4m3
// into kvq[node][32][K8|V8] via HW v_cvt_pk_fp8_f32; dead f16 K/V stores skipped.
template <bool HAS_CFH, bool HAS_CH, bool HAS_CHT, bool HAS_KVQ>
__global__ __launch_bounds__(256) void gemm_tn_f16(const _Float16* __restrict__ A,
                                                   const _Float16* __restrict__ Bt,
                                                   const float* __restrict__ bias,
                                                   _Float16* __restrict__ Cfh, int NF,
                                                   _Float16* __restrict__ Ch, int choff, int ldh,
                                                   _Float16* __restrict__ ChT, int ldt,
                                                   unsigned char* __restrict__ kvq,
                                                   int M, int N, int K) {
  __shared__ __align__(16) char smA[32768];
  __shared__ __align__(16) char smB[32768];
  const int tid = threadIdx.x;
  const int wid = tid >> 6, lane = tid & 63;
  const int wr = wid >> 1, wc = wid & 1;
  const int il = lane & 15, g = lane >> 4;
  const int row0 = blockIdx.y * 128;
  const int col0 = blockIdx.x * 128;
  {
    const f16x8* Ag = reinterpret_cast<const f16x8*>(A + (size_t)row0 * 128);
    const f16x8* Bg = reinterpret_cast<const f16x8*>(Bt + (size_t)col0 * 128);
#pragma unroll
    for (int it = 0; it < 8; ++it) {
      const int c = it * 256 + tid;
      const int r = c >> 4;
      const int off = r * 256 + (((c & 15) << 4) ^ ((r & 7) << 4));
      f16x8 va = Ag[c];
      f16x8 vb = Bg[c];
      *reinterpret_cast<f16x8*>(smA + off) = va;
      *reinterpret_cast<f16x8*>(smB + off) = vb;
    }
  }
  __syncthreads();
  f32x4 acc[4][4];
#pragma unroll
  for (int a = 0; a < 4; ++a)
#pragma unroll
    for (int b = 0; b < 4; ++b) acc[a][b] = (f32x4){0.f, 0.f, 0.f, 0.f};
#pragma unroll
  for (int ks = 0; ks < 4; ++ks) {
    const int kb = ks * 64 + g * 16;
    f16x8 af[4], bf[4];
#pragma unroll
    for (int f = 0; f < 4; ++f) {
      const int ra = wr * 64 + f * 16 + il;
      const int rb = wc * 64 + f * 16 + il;
      af[f] = *reinterpret_cast<const f16x8*>(smA + ra * 256 + (kb ^ ((ra & 7) << 4)));
      bf[f] = *reinterpret_cast<const f16x8*>(smB + rb * 256 + (kb ^ ((rb & 7) << 4)));
    }
#pragma unroll
    for (int fi = 0; fi < 4; ++fi)
#pragma unroll
      for (int fj = 0; fj < 4; ++fj)
        acc[fi][fj] = __builtin_amdgcn_mfma_f32_16x16x32_f16(bf[fj], af[fi], acc[fi][fj], 0, 0, 0);
  }
#pragma unroll
  for (int fi = 0; fi < 4; ++fi) {
    const int row = row0 + wr * 64 + fi * 16 + il;
#pragma unroll
    for (int fj = 0; fj < 4; ++fj) {
      const int col = col0 + wc * 64 + fj * 16 + g * 4;
      const float4 b4 = *reinterpret_cast<const float4*>(bias + col);
      float v0 = acc[fi][fj][0] + b4.x, v1 = acc[fi][fj][1] + b4.y;
      float v2 = acc[fi][fj][2] + b4.z, v3 = acc[fi][fj][3] + b4.w;
      f16x4 o;
      o[0] = (_Float16)v0; o[1] = (_Float16)v1; o[2] = (_Float16)v2; o[3] = (_Float16)v3;
      const int ch = col - choff;  // channel within QKVS row
      if constexpr (HAS_CFH) {
        if (col < NF) *reinterpret_cast<f16x4*>(&Cfh[(size_t)row * NF + col]) = o;
      }
      if constexpr (HAS_CH) {
        const bool kvrange = HAS_KVQ && (ch >= 256 && ch < 768);
        if (col >= choff && !kvrange)
          *reinterpret_cast<f16x4*>(&Ch[(size_t)row * ldh + ch]) = o;
      }
      if constexpr (HAS_KVQ) {
        if (ch >= 256 && ch < 768) {
          const int c = (ch >= 512) ? (ch - 512) : (ch - 256);
          const int boff = ((c >> 3) << 4) + (c & 7) + ((ch >= 512) ? 8 : 0);
          unsigned pk = cvt2fp8<false>(0u, v0, v1);
          pk = cvt2fp8<true>(pk, v2, v3);
          *reinterpret_cast<unsigned*>(kvq + (size_t)row * 512 + boff) = pk;
        }
      }
      if constexpr (HAS_CHT) {
#pragma unroll
        for (int i = 0; i < 4; ++i) ChT[(size_t)(col + i) * ldt + row] = o[i];
      }
    }
  }
}

// ---------------- fused per-node attention: fp8 K/V gather, single-pass online softmax --
__global__ __launch_bounds__(256) void node_attn_ln_kernel(
    const _Float16* __restrict__ QKVSh, const unsigned char* __restrict__ kvq,
    const _Float16* __restrict__ epth,
    const _Float16* __restrict__ hpre,
    const int* __restrict__ offs, const unsigned* __restrict__ epk,
    const int* __restrict__ order,
    const float* __restrict__ gamma, const float* __restrict__ beta,
    _Float16* __restrict__ hlnh, int Nn) {
  __shared__ float sqe[4][2][10];
  __shared__ __align__(16) _Float16 elds[2560];
  const int tid = threadIdx.x;
  for (int t = tid; t < 1280; t += 256)
    reinterpret_cast<unsigned*>(elds)[t] = reinterpret_cast<const unsigned*>(epth)[t];
  __syncthreads();
  const int w = tid >> 6, lane = tid & 63;
  const int i = order[blockIdx.x * 4 + w];
  const int sub = lane >> 5;
  const int r = lane & 31;
  const int half = r >> 4;
  const int co = r << 3;
  const float scale = 0.08838834764831845f;  // 1/sqrt(128)
  f16x8 qh = *reinterpret_cast<const f16x8*>(QKVSh + (size_t)i * QW + co);
  const f16x2* q2 = reinterpret_cast<const f16x2*>(&qh);
  float qf[8];
#pragma unroll
  for (int t = 0; t < 8; ++t) qf[t] = (float)qh[t] * scale;
#pragma unroll
  for (int ty = 0; ty < 10; ++ty) {
    f16x8 ev = *reinterpret_cast<const f16x8*>(elds + (ty << 8) + co);
    const f16x2* e2 = reinterpret_cast<const f16x2*>(&ev);
    float s = 0.f;
#pragma unroll
    for (int p2 = 0; p2 < 4; ++p2) s = fdot2f(q2[p2], e2[p2], s);
    s += __shfl_xor(s, 1); s += __shfl_xor(s, 2);
    s += __shfl_xor(s, 4); s += __shfl_xor(s, 8);
    if (lane < 32 && (r & 15) == 0) sqe[w][half][ty] = s * scale;
  }
  __threadfence_block();
  float m_me = -1e30f, s_me = 0.f;
  float acc[8] = {0.f};
  const int ebeg = offs[i], eend = offs[i + 1];
  if (ebeg < eend) {
    const int last = eend - 1;
    unsigned pk0 = epk[min(ebeg + sub, last)];
    unsigned pk1 = epk[min(ebeg + 2 + sub, last)];
    uint4 kv0 = *reinterpret_cast<const uint4*>(kvq + (size_t)(pk0 & 0x3FFFF) * 512 + (r << 4));
    uint4 kv1 = *reinterpret_cast<const uint4*>(kvq + (size_t)(pk1 & 0x3FFFF) * 512 + (r << 4));
    for (int j = ebeg; j < eend; j += 2) {
      const uint4 cur = kv0;
      const unsigned pkc = pk0;
      kv0 = kv1; pk0 = pk1;
      pk1 = epk[min(j + 4 + sub, last)];
      kv1 = *reinterpret_cast<const uint4*>(kvq + (size_t)(pk1 & 0x3FFFF) * 512 + (r << 4));
      const int tyc = pkc >> 18;
      // decode K (8 fp8 in cur.x, cur.y), dot with pre-scaled qf
      f32x2 k0 = fp8x2f<false>(cur.x), k1 = fp8x2f<true>(cur.x);
      f32x2 k2 = fp8x2f<false>(cur.y), k3 = fp8x2f<true>(cur.y);
      float d = qf[0] * k0[0];
      d = fmaf(qf[1], k0[1], d); d = fmaf(qf[2], k1[0], d); d = fmaf(qf[3], k1[1], d);
      d = fmaf(qf[4], k2[0], d); d = fmaf(qf[5], k2[1], d);
      d = fmaf(qf[6], k3[0], d); d = fmaf(qf[7], k3[1], d);
      d += __shfl_xor(d, 1); d += __shfl_xor(d, 2);
      d += __shfl_xor(d, 4); d += __shfl_xor(d, 8);
      d += sqe[w][half][tyc];
      float e;
      if (d > m_me + 8.f) {  // defer-max: fires ~once per node
        const float rr = __expf(m_me - d);
        s_me *= rr;
#pragma unroll
        for (int t = 0; t < 8; ++t) acc[t] *= rr;
        m_me = d;
        e = 1.f;
      } else {
        e = __expf(d - m_me);
      }
      if (j + sub >= eend) e = 0.f;  // odd-tail mask
      s_me += e;
      // decode V (cur.z, cur.w); acc += (v + ept)*e
      f32x2 v0 = fp8x2f<false>(cur.z), v1 = fp8x2f<true>(cur.z);
      f32x2 v2 = fp8x2f<false>(cur.w), v3 = fp8x2f<true>(cur.w);
      f16x8 ec = *reinterpret_cast<const f16x8*>(elds + (tyc << 8) + co);
      acc[0] = fmaf(v0[0], e, acc[0]); acc[1] = fmaf(v0[1], e, acc[1]);
      acc[2] = fmaf(v1[0], e, acc[2]); acc[3] = fmaf(v1[1], e, acc[3]);
      acc[4] = fmaf(v2[0], e, acc[4]); acc[5] = fmaf(v2[1], e, acc[5]);
      acc[6] = fmaf(v3[0], e, acc[6]); acc[7] = fmaf(v3[1], e, acc[7]);
#pragma unroll
      for (int t = 0; t < 8; ++t) acc[t] = fmaf((float)ec[t], e, acc[t]);
    }
  }
  // merge the two edge slots (lane^32 holds same (half, co))
  const float mo = __shfl_xor(m_me, 32);
  const float so = __shfl_xor(s_me, 32);
  const float mf = fmaxf(m_me, mo);
  const float sc_me = __expf(m_me - mf);
  const float sc_o = __expf(mo - mf);
  const float s_tot = s_me * sc_me + so * sc_o;
  const float invme = 1.f / (s_tot + 1e-16f);
  float g[8];
#pragma unroll
  for (int t = 0; t < 8; ++t) {
    const float ao = __shfl_xor(acc[t], 32);
    const float a = (acc[t] * sc_me + ao * sc_o) * invme;
    g[t] = 0.5f * (a + __shfl_xor(a, 16));  // head mean
  }
  const int cm = (r & 15) << 3;
  f16x8 sk = *reinterpret_cast<const f16x8*>(QKVSh + (size_t)i * QW + 768 + cm);
  f16x8 pr = *reinterpret_cast<const f16x8*>(hpre + (size_t)i * DD + cm);
  float xv[8];
#pragma unroll
  for (int t = 0; t < 8; ++t) xv[t] = g[t] + (float)sk[t] + (float)pr[t];
  float sm = 0.f;
#pragma unroll
  for (int t = 0; t < 8; ++t) sm += xv[t];
  sm += __shfl_xor(sm, 1); sm += __shfl_xor(sm, 2);
  sm += __shfl_xor(sm, 4); sm += __shfl_xor(sm, 8);
  const float mu = sm * (1.f / 128.f);
  float dx[8], vvs = 0.f;
#pragma unroll
  for (int t = 0; t < 8; ++t) { dx[t] = xv[t] - mu; vvs += dx[t] * dx[t]; }
  vvs += __shfl_xor(vvs, 1); vvs += __shfl_xor(vvs, 2);
  vvs += __shfl_xor(vvs, 4); vvs += __shfl_xor(vvs, 8);
  const float rstd = rsqrtf(vvs * (1.f / 128.f) + 1e-6f);
  if (lane < 16) {
    float4 gm0 = *reinterpret_cast<const float4*>(gamma + cm);
    float4 gm1 = *reinterpret_cast<const float4*>(gamma + cm + 4);
    float4 bt0 = *reinterpret_cast<const float4*>(beta + cm);
    float4 bt1 = *reinterpret_cast<const float4*>(beta + cm + 4);
    f16x8 o;
    o[0] = (_Float16)(dx[0] * rstd * gm0.x + bt0.x);
    o[1] = (_Float16)(dx[1] * rstd * gm0.y + bt0.y);
    o[2] = (_Float16)(dx[2] * rstd * gm0.z + bt0.z);
    o[3] = (_Float16)(dx[3] * rstd * gm0.w + bt0.w);
    o[4] = (_Float16)(dx[4] * rstd * gm1.x + bt1.x);
    o[5] = (_Float16)(dx[5] * rstd * gm1.y + bt1.y);
    o[6] = (_Float16)(dx[6] * rstd * gm1.z + bt1.z);
    o[7] = (_Float16)(dx[7] * rstd * gm1.w + bt1.w);
    *reinterpret_cast<f16x8*>(hlnh + (size_t)i * DD + cm) = o;
  }
}

// ---------------- final: gather mask rows of hln1, apply layer-1 fused FFN ----------------
__global__ __launch_bounds__(128) void final_kernel(const _Float16* __restrict__ hlnh1,
                                                    const float* __restrict__ Wf,
                                                    const float* __restrict__ bfv,
                                                    const int* __restrict__ midx,
                                                    float* __restrict__ out) {
  __shared__ float rowv[128];
  const int b = blockIdx.x, j = threadIdx.x;
  const int row = midx[b];
  rowv[j] = (float)hlnh1[(size_t)row * DD + j];
  __syncthreads();
  const float* w1 = Wf + 16384 + j;
  float s = bfv[128 + j];
#pragma unroll 4
  for (int c = 0; c < 128; ++c) s = fmaf(rowv[c], w1[c * 128], s);
  out[b * DD + j] = s;
}

extern "C" void kernel_launch(void* const* d_in, const int* in_sizes, int n_in,
                              void* d_out, int out_size, void* d_ws, size_t ws_size,
                              hipStream_t stream) {
  const float* x    = (const float*)d_in[0];
  const float* hemb = (const float*)d_in[1];
  const float* Wq   = (const float*)d_in[2];
  const float* bq   = (const float*)d_in[3];
  const float* Wk   = (const float*)d_in[4];
  const float* bk   = (const float*)d_in[5];
  const float* Wv   = (const float*)d_in[6];
  const float* bv   = (const float*)d_in[7];
  const float* We   = (const float*)d_in[8];
  const float* Wsk  = (const float*)d_in[9];
  const float* bsk  = (const float*)d_in[10];
  const float* lng  = (const float*)d_in[11];
  const float* lnb  = (const float*)d_in[12];
  const float* fw1  = (const float*)d_in[13];
  const float* fb1  = (const float*)d_in[14];
  const float* fw2  = (const float*)d_in[15];
  const float* fb2  = (const float*)d_in[16];
  const int* eidx   = (const int*)d_in[17];
  const int* etyp   = (const int*)d_in[18];
  const int* midx   = (const int*)d_in[19];

  const int Nn = in_sizes[0] / DD;     // 16000
  const int E = in_sizes[18];          // 256000

  const int* esrc = eidx;
  const int* edst = eidx + E;

  char* p = (char*)d_ws;
  auto alloc = [&](size_t bytes) -> void* {
    void* r = (void*)p;
    p += (bytes + 255) & ~(size_t)255;
    return r;
  };
  _Float16* QKVSh = (_Float16*)alloc((size_t)Nn * QW * 2);
  unsigned char* kvq = (unsigned char*)alloc((size_t)Nn * 512);
  _Float16* xh    = (_Float16*)alloc((size_t)Nn * DD * 2);
  _Float16* hln0  = (_Float16*)alloc((size_t)Nn * DD * 2);
  _Float16* hln1  = (_Float16*)alloc((size_t)Nn * DD * 2);
  _Float16* h1h   = (_Float16*)alloc((size_t)Nn * DD * 2);
  _Float16* WcatT = (_Float16*)alloc((size_t)QW * DD * 2);
  float*    Wcat  = (float*)alloc((size_t)DD * QW * 4);
  float*    bcat  = (float*)alloc(QW * 4);
  _Float16* epth  = (_Float16*)alloc(2560 * 2);
  _Float16* fw1h  = (_Float16*)alloc((size_t)2 * DD * 512 * 2);
  _Float16* fw2Th = (_Float16*)alloc((size_t)2 * DD * 512 * 2);
  float*    Wf    = (float*)alloc(2 * 128 * 128 * 4);
  _Float16* Wfh   = (_Float16*)alloc(128 * 128 * 2);
  float*    bfv   = (float*)alloc(256 * 4);
  float*    bzero = (float*)alloc(1024 * 4);
  _Float16* BtMid = (_Float16*)alloc((size_t)1024 * 128 * 2);
  float*    bmid  = (float*)alloc(1024 * 4);
  int* offs   = (int*)alloc((size_t)(Nn + 1) * 4);
  int* bbase  = (int*)alloc((NB + 1) * 4);
  int* bcursor= (int*)alloc((NB + 1) * 4);
  int* dcur   = (int*)alloc(64 * 4);
  int* order  = (int*)alloc((size_t)Nn * 4);
  const int nsblk = (E + 2047) / 2048;
  int* bparts = (int*)alloc((size_t)nsblk * 128 * 4);
  int* dparts = (int*)alloc((size_t)NB * 64 * 4);
  unsigned* ebuf = (unsigned*)alloc((size_t)E * 4);
  unsigned* epk  = (unsigned*)alloc((size_t)E * 4);

  // CSR build (no memsets: partial histograms)
  csr_count<<<nsblk, 256, 0, stream>>>(edst, bparts, E);
  csr_scan<<<1, 128, 0, stream>>>(bparts, nsblk, bbase, bcursor, offs, E, Nn);
  csr_scatter<<<nsblk, 256, 0, stream>>>(edst, esrc, etyp, bcursor, ebuf, E);
  csr_fine<<<NB, 256, 0, stream>>>(ebuf, bbase, epk, offs, dparts);
  deg_scan<<<1, 64, 0, stream>>>(dparts, NB, dcur);
  deg_order<<<(Nn + 255) / 256, 256, 0, stream>>>(offs, dcur, order, Nn);

  // Precompute (pp_cast includes fw2 transpose tail blocks)
  const int pc_threads = 256 + 2560 + 114688 + 896 + 1024 + 16384 + Nn * 16;
  const int nb0 = (pc_threads + 255) / 256;
  pp_cast<<<nb0 + 32, 256, 0, stream>>>(
      Wq, Wk, Wv, Wsk, bq, bk, bv, bsk, hemb, We, x, fw1, fb1, fw2, fb2,
      WcatT, Wcat, bcat, epth, xh, fw1h, fw2Th, bfv, bzero, Nn, nb0);
  pp_bmid<<<4, 256, 0, stream>>>(bfv, Wcat, bcat, bmid);
  wf_gemm<<<dim3(1, 1, 2), 256, 0, stream>>>(fw1h, fw2Th, Wf, Wfh, BtMid);
  // BtMid rows 128..1023 = (Wf0 @ Wcat)^T
  gemm_tn_f16<false, false, true, false><<<dim3(7, 1), 256, 0, stream>>>(
      Wfh, WcatT, bzero, nullptr, 0, nullptr, 0, 0, BtMid + 16384, 128, nullptr,
      128, 896, 128);

  // Layer 0: QKVS0 = xh @ Wcat + bcat (K/V also emitted as fp8 kvq)
  gemm_tn_f16<false, true, false, true><<<dim3(QW / 128, Nn / 128), 256, 0, stream>>>(
      xh, WcatT, bcat, nullptr, 0, QKVSh, 0, QW, nullptr, 0, kvq, Nn, QW, DD);
  node_attn_ln_kernel<<<Nn / 4, 256, 0, stream>>>(QKVSh, kvq, epth, xh, offs, epk, order,
                                                  lng, lnb, hln0, Nn);
  // Fused: [h1h (f16) | QKVS1 (f16) + kvq fp8] = hln0 @ [Wf0 | Wf0@Wcat] + bmid
  gemm_tn_f16<true, true, false, true><<<dim3(1024 / 128, Nn / 128), 256, 0, stream>>>(
      hln0, BtMid, bmid, h1h, 128, QKVSh, 128, QW, nullptr, 0, kvq, Nn, 1024, DD);
  node_attn_ln_kernel<<<Nn / 4, 256, 0, stream>>>(QKVSh, kvq, epth, h1h, offs, epk, order,
                                                  lng + DD, lnb + DD, hln1, Nn);
  final_kernel<<<64, 128, 0, stream>>>(hln1, Wf, bfv, midx, (float*)d_out);
}